// Round 10
// baseline (367.263 us; speedup 1.0000x reference)
//
#include <hip/hip_runtime.h>
#include <math.h>
#include <float.h>

#define NEG_SLOPE 0.2f
#define NCHUNK 128   // edge-array chunks for the deterministic scatter

typedef short short8 __attribute__((ext_vector_type(8)));
typedef float f32x4  __attribute__((ext_vector_type(4)));

__device__ __forceinline__ unsigned short bf16hi(float x) {
    unsigned u = __float_as_uint(x);
    return (unsigned short)((u + 0x7FFFu + ((u >> 16) & 1u)) >> 16);
}
__device__ __forceinline__ float bf16tof(unsigned short h) {
    return __uint_as_float(((unsigned)h) << 16);
}

// K1: h = x @ W_gat (N x 11 @ 11 x 64) fp32, a_src/a_dst; blocks 0-7 also do
// weight prep (W1/W2 -> MFMA b-frag bf16 hi/lo) and block 0 softmax(alpha).
__global__ __launch_bounds__(256) void gat_input_kernel(
    const float* __restrict__ x, const float* __restrict__ Wg,
    const float* __restrict__ att_src, const float* __restrict__ att_dst,
    float* __restrict__ h, float* __restrict__ a_src, float* __restrict__ a_dst, int N,
    const float* __restrict__ W1l, const float* __restrict__ W1r,
    const float* __restrict__ W2l, const float* __restrict__ W2r,
    unsigned short* __restrict__ W1hi, unsigned short* __restrict__ W1lo,
    unsigned short* __restrict__ W2hi, unsigned short* __restrict__ W2lo,
    const float* __restrict__ alpha, float* __restrict__ wsm)
{
    // ---- folded weight prep (blocks 0..7) ----
    if (blockIdx.x < 8) {
        if (blockIdx.x == 0 && threadIdx.x == 0) {
            float m = alpha[0];
            for (int i = 1; i < 4; i++) m = fmaxf(m, alpha[i]);
            float e[4], s = 0.f;
            for (int i = 0; i < 4; i++) { e[i] = expf(alpha[i] - m); s += e[i]; }
            for (int i = 0; i < 4; i++) wsm[i] = e[i] / s;
        }
        int which = blockIdx.x >> 2;
        const float* Wl = which ? W2l : W1l;
        const float* Wr = which ? W2r : W1r;
        unsigned short* Whi = which ? W2hi : W1hi;
        unsigned short* Wlo = which ? W2lo : W1lo;
        int idx = (blockIdx.x & 3) * 256 + threadIdx.x;   // 0..1023
        int kc = idx >> 9, rem = idx & 511;
        int t = rem >> 6, ln = rem & 63;
        int quad = ln >> 4, col16 = ln & 15;
        int c = t * 16 + col16;
        #pragma unroll
        for (int j = 0; j < 8; j++) {
            int k = kc * 32 + quad * 8 + j;
            float w = (c < 64) ? Wl[k * 64 + c] : Wr[k * 64 + (c - 64)];
            unsigned short hi = bf16hi(w);
            unsigned short lo = bf16hi(w - bf16tof(hi));
            Whi[(size_t)idx * 8 + j] = hi;
            Wlo[(size_t)idx * 8 + j] = lo;
        }
    }
    // ---- main duty ----
    __shared__ float Wl[11 * 64];
    int tid = threadIdx.x;
    for (int i = tid; i < 11 * 64; i += 256) Wl[i] = Wg[i];
    __syncthreads();
    int lane = tid & 63;
    int n = blockIdx.x * 4 + (tid >> 6);
    if (n >= N) return;
    float xv = (lane < 11) ? x[n * 11 + lane] : 0.f;
    float acc = 0.f;
    #pragma unroll
    for (int k = 0; k < 11; k++) acc += __shfl(xv, k, 64) * Wl[k * 64 + lane];
    h[(size_t)n * 64 + lane] = acc;
    float ps = acc * att_src[lane];
    float pd = acc * att_dst[lane];
    for (int off = 32; off; off >>= 1) {
        ps += __shfl_down(ps, off, 64);
        pd += __shfl_down(pd, off, 64);
    }
    if (lane == 0) { a_src[n] = ps; a_dst[n] = pd; }
}

// ---- Chunked CSR construction (bucket = dst >> 7; no global atomics) ----
// ebuf entry packed: (src << 7) | (dst & 127)  [src < 2^17, fits 24 bits]

__global__ __launch_bounds__(1024) void edge_hist_kernel(
    const int* __restrict__ dst, int* __restrict__ hist, int E, int NBK)
{
    __shared__ int c[1024];
    int t = threadIdx.x;
    c[t] = 0;
    __syncthreads();
    int chunk = (E + NCHUNK - 1) / NCHUNK;
    int lo = blockIdx.x * chunk;
    int hi = lo + chunk; if (hi > E) hi = E;
    for (int i = lo + t; i < hi; i += 1024)
        atomicAdd(&c[dst[i] >> 7], 1);
    __syncthreads();
    if (t < NBK) hist[t * NCHUNK + blockIdx.x] = c[t];
}

__global__ __launch_bounds__(1024) void edge_scatter_kernel(
    const int* __restrict__ src, const int* __restrict__ dst,
    const int* __restrict__ rstart, unsigned* __restrict__ ebuf, int E, int NBK)
{
    __shared__ int cur[1024];
    int t = threadIdx.x;
    if (t < NBK) cur[t] = rstart[t * NCHUNK + blockIdx.x];
    __syncthreads();
    int chunk = (E + NCHUNK - 1) / NCHUNK;
    int lo = blockIdx.x * chunk;
    int hi = lo + chunk; if (hi > E) hi = E;
    for (int i = lo + t; i < hi; i += 1024) {
        int d = dst[i];
        int p = atomicAdd(&cur[d >> 7], 1);
        ebuf[p] = ((unsigned)src[i] << 7) | (unsigned)(d & 127);
    }
}

// ---- generic exclusive scan ----
__global__ __launch_bounds__(256) void scan_reduce_kernel(
    const int* __restrict__ v, int* __restrict__ bsum, int M)
{
    __shared__ int s[256];
    int t = threadIdx.x;
    int base = blockIdx.x * 1024 + t * 4;
    int sum = 0;
    #pragma unroll
    for (int j = 0; j < 4; j++) { int idx = base + j; if (idx < M) sum += v[idx]; }
    s[t] = sum; __syncthreads();
    for (int off = 128; off; off >>= 1) {
        if (t < off) s[t] += s[t + off];
        __syncthreads();
    }
    if (t == 0) bsum[blockIdx.x] = s[0];
}

__global__ __launch_bounds__(256) void scan_spine_kernel(
    const int* __restrict__ bsum, int* __restrict__ boff, int NB)
{
    __shared__ int s[256];
    int t = threadIdx.x;
    int v = (t < NB) ? bsum[t] : 0;
    s[t] = v; __syncthreads();
    for (int off = 1; off < 256; off <<= 1) {
        int x = (t >= off) ? s[t - off] : 0;
        __syncthreads();
        s[t] += x;
        __syncthreads();
    }
    if (t < NB) boff[t] = s[t] - v;
}

__global__ __launch_bounds__(256) void scan_apply_kernel(
    const int* __restrict__ v, const int* __restrict__ boff,
    int* __restrict__ out, int M)
{
    __shared__ int s[256];
    int t = threadIdx.x;
    int base = blockIdx.x * 1024;
    int vv[4]; int sum = 0;
    #pragma unroll
    for (int j = 0; j < 4; j++) {
        int idx = base + t * 4 + j;
        vv[j] = (idx < M) ? v[idx] : 0;
        sum += vv[j];
    }
    s[t] = sum; __syncthreads();
    for (int off = 1; off < 256; off <<= 1) {
        int x = (t >= off) ? s[t - off] : 0;
        __syncthreads();
        s[t] += x;
        __syncthreads();
    }
    int ex = s[t] - sum + boff[blockIdx.x];
    #pragma unroll
    for (int j = 0; j < 4; j++) {
        int idx = base + t * 4 + j;
        if (idx < M) out[idx] = ex;
        ex += vv[j];
    }
}

// one workgroup per bucket: LDS per-dst counts -> LDS scan -> cnt/rowstart -> scatter csr
__global__ __launch_bounds__(256) void bucket_build_kernel(
    const unsigned* __restrict__ ebuf, const int* __restrict__ rstart,
    int* __restrict__ cnt, int* __restrict__ rowstart,
    int* __restrict__ csr, int E, int N, int NBK)
{
    __shared__ int c[128];
    __shared__ int rs[128];
    __shared__ int cur[128];
    int b = blockIdx.x, t = threadIdx.x;
    if (t < 128) { c[t] = 0; cur[t] = 0; }
    __syncthreads();
    int beg = rstart[b * NCHUNK];
    int end = (b == NBK - 1) ? E : rstart[(b + 1) * NCHUNK];
    int n = end - beg;
    for (int j = t; j < n; j += 256)
        atomicAdd(&c[ebuf[beg + j] & 127u], 1);
    __syncthreads();
    int myc = (t < 128) ? c[t] : 0;
    if (t < 128) rs[t] = myc;
    __syncthreads();
    for (int off = 1; off < 128; off <<= 1) {
        int v = (t < 128 && t >= off) ? rs[t - off] : 0;
        __syncthreads();
        if (t < 128) rs[t] += v;
        __syncthreads();
    }
    int ex = (t < 128) ? (rs[t] - myc) : 0;
    __syncthreads();
    if (t < 128) rs[t] = ex;
    int base = b << 7;
    if (t < 128 && base + t < N) {
        cnt[base + t] = myc;
        rowstart[base + t] = beg + ex;
    }
    __syncthreads();
    for (int j = t; j < n; j += 256) {
        unsigned e = ebuf[beg + j];
        int d = (int)(e & 127u);
        int p = atomicAdd(&cur[d], 1);
        csr[beg + rs[d] + p] = (int)(e >> 7);
    }
}

// K2: GAT gather — wave per dst node, plain exp softmax (logits bounded), float4 gathers
__global__ __launch_bounds__(256) void gat_gather_kernel(
    const float* __restrict__ h, const float* __restrict__ a_src,
    const float* __restrict__ a_dst, const float* __restrict__ bg,
    const int* __restrict__ rowstart, const int* __restrict__ cnt,
    const int* __restrict__ csr, const float* __restrict__ wsm,
    float* __restrict__ hgat, float* __restrict__ outD, int N)
{
    const float4* __restrict__ h4 = (const float4*)h;
    int d = blockIdx.x * 4 + (threadIdx.x >> 6);
    int lane = threadIdx.x & 63;
    if (d >= N) return;
    int grp = lane >> 4;
    int sub = lane & 15;
    float ad = a_dst[d];
    int beg = rowstart[d], deg = cnt[d];
    float a0 = a_src[d] + ad;
    float lg0 = a0 > 0.f ? a0 : NEG_SLOPE * a0;
    float w_self = expf(lg0);
    float l_lane = 0.f;
    float4 accA = make_float4(0.f, 0.f, 0.f, 0.f);
    float4 accB = make_float4(0.f, 0.f, 0.f, 0.f);
    if (grp == 0) {
        float4 hv = h4[(size_t)d * 16 + sub];
        accA.x = w_self * hv.x; accA.y = w_self * hv.y;
        accA.z = w_self * hv.z; accA.w = w_self * hv.w;
    }
    for (int base = 0; base < deg; base += 64) {
        int eidx = base + lane;
        bool valid = eidx < deg;
        int sid = valid ? csr[beg + eidx] : 0;
        float aa = a_src[sid] + ad;
        float lg = aa > 0.f ? aa : NEG_SLOPE * aa;
        float w = valid ? expf(lg) : 0.f;
        l_lane += w;
        int nv = deg - base; if (nv > 64) nv = 64;
        for (int j = 0; j < nv; j += 16) {
            int e0 = j + grp,      e1 = j + 4 + grp;
            int e2 = j + 8 + grp,  e3 = j + 12 + grp;
            int   i0 = __shfl(sid, e0, 64); float w0 = __shfl(w, e0, 64);
            int   i1 = __shfl(sid, e1, 64); float w1 = __shfl(w, e1, 64);
            int   i2 = __shfl(sid, e2, 64); float w2 = __shfl(w, e2, 64);
            int   i3 = __shfl(sid, e3, 64); float w3 = __shfl(w, e3, 64);
            float4 v0 = h4[(size_t)i0 * 16 + sub];
            float4 v1 = h4[(size_t)i1 * 16 + sub];
            float4 v2 = h4[(size_t)i2 * 16 + sub];
            float4 v3 = h4[(size_t)i3 * 16 + sub];
            accA.x += w0 * v0.x + w1 * v1.x; accB.x += w2 * v2.x + w3 * v3.x;
            accA.y += w0 * v0.y + w1 * v1.y; accB.y += w2 * v2.y + w3 * v3.y;
            accA.z += w0 * v0.z + w1 * v1.z; accB.z += w2 * v2.z + w3 * v3.z;
            accA.w += w0 * v0.w + w1 * v1.w; accB.w += w2 * v2.w + w3 * v3.w;
        }
    }
    for (int off = 32; off; off >>= 1) l_lane += __shfl_xor(l_lane, off, 64);
    float l = l_lane + w_self;
    float4 acc;
    acc.x = accA.x + accB.x; acc.y = accA.y + accB.y;
    acc.z = accA.z + accB.z; acc.w = accA.w + accB.w;
    #pragma unroll
    for (int off = 16; off <= 32; off <<= 1) {
        acc.x += __shfl_xor(acc.x, off, 64);
        acc.y += __shfl_xor(acc.y, off, 64);
        acc.z += __shfl_xor(acc.z, off, 64);
        acc.w += __shfl_xor(acc.w, off, 64);
    }
    float inv = 1.0f / (l + 1e-16f);
    const float4* bg4 = (const float4*)bg;
    float4 bb = bg4[sub];
    float4 out;
    out.x = acc.x * inv + bb.x; out.y = acc.y * inv + bb.y;
    out.z = acc.z * inv + bb.z; out.w = acc.w * inv + bb.w;
    size_t idx = (size_t)d * 16 + sub;
    if (grp == 0) ((float4*)hgat)[idx] = out;
    if (grp == 1) {
        float w0 = wsm[0];
        float4 o; o.x = w0 * out.x; o.y = w0 * out.y; o.z = w0 * out.z; o.w = w0 * out.w;
        ((float4*)outD)[idx] = o;
    }
}

// K6: dense GEMM [P|Q] = hin @ [Wl|Wr] (+b on Q half) via mfma 16x16x32 bf16x3.
__global__ __launch_bounds__(256) void sage_gemm_kernel(
    const float* __restrict__ hin,
    const unsigned short* __restrict__ Whi, const unsigned short* __restrict__ Wlo,
    const float* __restrict__ bvec,
    float* __restrict__ P, float* __restrict__ Q, int N)
{
    int wave = threadIdx.x >> 6, lane = threadIdx.x & 63;
    int base = blockIdx.x * 64 + wave * 16;
    if (base >= N) return;
    int quad = lane >> 4, col16 = lane & 15;
    int m = base + col16;
    int mc = m < N ? m : N - 1;
    f32x4 acc[8];
    #pragma unroll
    for (int t = 0; t < 8; t++) acc[t] = (f32x4){0.f, 0.f, 0.f, 0.f};
    #pragma unroll
    for (int kc = 0; kc < 2; kc++) {
        const float* ap = hin + (size_t)mc * 64 + kc * 32 + quad * 8;
        float4 va = *(const float4*)ap;
        float4 vb = *(const float4*)(ap + 4);
        float av[8] = {va.x, va.y, va.z, va.w, vb.x, vb.y, vb.z, vb.w};
        short8 ahi, alo;
        #pragma unroll
        for (int j = 0; j < 8; j++) {
            unsigned short hh = bf16hi(av[j]);
            ahi[j] = (short)hh;
            alo[j] = (short)bf16hi(av[j] - bf16tof(hh));
        }
        #pragma unroll
        for (int t = 0; t < 8; t++) {
            size_t off = ((size_t)(kc * 8 + t) * 64 + lane) * 8;
            short8 bhi = *(const short8*)(Whi + off);
            short8 blo = *(const short8*)(Wlo + off);
            acc[t] = __builtin_amdgcn_mfma_f32_16x16x32_bf16(ahi, bhi, acc[t], 0, 0, 0);
            acc[t] = __builtin_amdgcn_mfma_f32_16x16x32_bf16(alo, bhi, acc[t], 0, 0, 0);
            acc[t] = __builtin_amdgcn_mfma_f32_16x16x32_bf16(ahi, blo, acc[t], 0, 0, 0);
        }
    }
    #pragma unroll
    for (int t = 0; t < 8; t++) {
        #pragma unroll
        for (int r = 0; r < 4; r++) {
            int node = base + quad * 4 + r;
            if (node < N) {
                float v = acc[t][r];
                if (t < 4) {
                    P[(size_t)node * 64 + t * 16 + col16] = v;
                } else {
                    int c = (t - 4) * 16 + col16;
                    Q[(size_t)node * 64 + c] = v + bvec[c];
                }
            }
        }
    }
}

// K7: SAGE post — h' = mean_nbr(P) + Q[d]; outD += w*h'; optional hout store.
__global__ __launch_bounds__(256) void sage_post_kernel(
    const float* __restrict__ P, const float* __restrict__ Q,
    const int* __restrict__ rowstart, const int* __restrict__ cnt,
    const int* __restrict__ csr, const float* __restrict__ wsm, int widx,
    float* __restrict__ hout, float* __restrict__ outD, int N)
{
    const float4* __restrict__ P4 = (const float4*)P;
    int d = blockIdx.x * 4 + (threadIdx.x >> 6);
    int lane = threadIdx.x & 63;
    if (d >= N) return;
    int grp = lane >> 4, sub = lane & 15;
    int beg = rowstart[d], deg = cnt[d];
    float4 s0 = make_float4(0.f,0.f,0.f,0.f), s1 = s0, s2 = s0, s3 = s0;
    for (int base = 0; base < deg; base += 64) {
        int nv = deg - base; if (nv > 64) nv = 64;
        int sid = (lane < nv) ? csr[beg + base + lane] : 0;
        for (int j = 0; j < nv; j += 16) {
            int e0 = j + grp,     e1 = j + 4 + grp;
            int e2 = j + 8 + grp, e3 = j + 12 + grp;
            int i0 = __shfl(sid, e0, 64);
            int i1 = __shfl(sid, e1, 64);
            int i2 = __shfl(sid, e2, 64);
            int i3 = __shfl(sid, e3, 64);
            if (e0 < nv) { float4 v = P4[(size_t)i0 * 16 + sub]; s0.x += v.x; s0.y += v.y; s0.z += v.z; s0.w += v.w; }
            if (e1 < nv) { float4 v = P4[(size_t)i1 * 16 + sub]; s1.x += v.x; s1.y += v.y; s1.z += v.z; s1.w += v.w; }
            if (e2 < nv) { float4 v = P4[(size_t)i2 * 16 + sub]; s2.x += v.x; s2.y += v.y; s2.z += v.z; s2.w += v.w; }
            if (e3 < nv) { float4 v = P4[(size_t)i3 * 16 + sub]; s3.x += v.x; s3.y += v.y; s3.z += v.z; s3.w += v.w; }
        }
    }
    float4 sv;
    sv.x = (s0.x + s1.x) + (s2.x + s3.x);
    sv.y = (s0.y + s1.y) + (s2.y + s3.y);
    sv.z = (s0.z + s1.z) + (s2.z + s3.z);
    sv.w = (s0.w + s1.w) + (s2.w + s3.w);
    #pragma unroll
    for (int off = 16; off <= 32; off <<= 1) {
        sv.x += __shfl_xor(sv.x, off, 64);
        sv.y += __shfl_xor(sv.y, off, 64);
        sv.z += __shfl_xor(sv.z, off, 64);
        sv.w += __shfl_xor(sv.w, off, 64);
    }
    float invd = 1.0f / fmaxf((float)deg, 1.0f);
    size_t idx = (size_t)d * 16 + sub;
    float4 q4 = ((const float4*)Q)[idx];
    float4 o;
    o.x = sv.x * invd + q4.x; o.y = sv.y * invd + q4.y;
    o.z = sv.z * invd + q4.z; o.w = sv.w * invd + q4.w;
    if (hout && grp == 0) ((float4*)hout)[idx] = o;
    if (grp == 1) {
        float w = wsm[widx];
        float4 dd = ((float4*)outD)[idx];
        dd.x += w * o.x; dd.y += w * o.y; dd.z += w * o.z; dd.w += w * o.w;
        ((float4*)outD)[idx] = dd;
    }
}

// K8: 16 lanes per label-edge (float4 rows): out[e] = dot(outf[a], outf[b])
__global__ __launch_bounds__(256) void link_pred_kernel(
    const int* __restrict__ eli, const float* __restrict__ outf,
    float* __restrict__ out, int EL)
{
    const float4* __restrict__ o4 = (const float4*)outf;
    int e = blockIdx.x * 16 + (threadIdx.x >> 4);
    int sub = threadIdx.x & 15;
    if (e >= EL) return;
    int a = eli[e], b = eli[EL + e];
    float4 pa = o4[(size_t)a * 16 + sub];
    float4 pb = o4[(size_t)b * 16 + sub];
    float p = pa.x * pb.x + pa.y * pb.y + pa.z * pb.z + pa.w * pb.w;
    for (int off = 8; off; off >>= 1) p += __shfl_xor(p, off, 64);
    if (sub == 0) out[e] = p;
}

extern "C" void kernel_launch(void* const* d_in, const int* in_sizes, int n_in,
                              void* d_out, int out_size, void* d_ws, size_t ws_size,
                              hipStream_t stream)
{
    const float* x      = (const float*)d_in[0];
    const int*   ei     = (const int*)d_in[1];
    const int*   eli    = (const int*)d_in[2];
    const float* Wg     = (const float*)d_in[3];
    const float* att_s  = (const float*)d_in[4];
    const float* att_d  = (const float*)d_in[5];
    const float* bg     = (const float*)d_in[6];
    const float* W1l    = (const float*)d_in[7];
    const float* W1r    = (const float*)d_in[8];
    const float* b1     = (const float*)d_in[9];
    const float* W2l    = (const float*)d_in[10];
    const float* W2r    = (const float*)d_in[11];
    const float* b2     = (const float*)d_in[12];
    const float* alpha  = (const float*)d_in[13];

    const int N  = in_sizes[0] / 11;
    const int E  = in_sizes[1] / 2;
    const int EL = in_sizes[2] / 2;
    const int NBK = (N + 127) >> 7;      // buckets of 128 dsts (<=1024)
    const int M   = NBK * NCHUNK;        // hist/rstart table size

    const int* src = ei;
    const int* dst = ei + E;

    // workspace layout
    float* A        = (float*)d_ws;              // N*64: h -> P1 -> P2
    float* B        = A + (size_t)N * 64;        // N*64: h_gat -> Q1/h1 -> Q2
    float* D        = B + (size_t)N * 64;        // N*64: ebuf (CSR build) then output accum
    float* a_src    = D + (size_t)N * 64;        // N
    float* a_dst    = a_src + N;                 // N
    int*   cnt      = (int*)(a_dst + N);         // N
    int*   rowstart = cnt + N;                   // N
    int*   hist     = rowstart + N;              // M  (bucket-major: [b*NCHUNK + c])
    int*   rstart   = hist + M;                  // M  (exclusive scan of hist)
    int*   bsum     = rstart + M;                // 256
    int*   boff     = bsum + 256;                // 256
    int*   csr      = boff + 256;                // E
    unsigned short* wf = (unsigned short*)(csr + E);  // 4 x 8192 ushorts
    unsigned short* W1hi = wf;
    unsigned short* W1lo = wf + 8192;
    unsigned short* W2hi = wf + 16384;
    unsigned short* W2lo = wf + 24576;
    float* wsm      = (float*)(wf + 32768);      // 4
    unsigned* ebuf  = (unsigned*)D;              // E packed entries — dead before gat_gather writes D

    // gat_input (+ folded weight prep + softmax(alpha))
    gat_input_kernel<<<(N + 3) / 4, 256, 0, stream>>>(x, Wg, att_s, att_d, A, a_src, a_dst, N,
                                                      W1l, W1r, W2l, W2r,
                                                      W1hi, W1lo, W2hi, W2lo, alpha, wsm);

    // Chunked CSR build (no global atomics, XCD-local writes)
    edge_hist_kernel<<<NCHUNK, 1024, 0, stream>>>(dst, hist, E, NBK);
    int NB = (M + 1023) / 1024;
    scan_reduce_kernel<<<NB, 256, 0, stream>>>(hist, bsum, M);
    scan_spine_kernel<<<1, 256, 0, stream>>>(bsum, boff, NB);
    scan_apply_kernel<<<NB, 256, 0, stream>>>(hist, boff, rstart, M);
    edge_scatter_kernel<<<NCHUNK, 1024, 0, stream>>>(src, dst, rstart, ebuf, E, NBK);
    bucket_build_kernel<<<NBK, 256, 0, stream>>>(ebuf, rstart, cnt, rowstart, csr, E, N, NBK);

    // GAT: read h (A) -> h_gat (B), D = w0*h_gat  (overwrites ebuf — now dead)
    gat_gather_kernel<<<(N + 3) / 4, 256, 0, stream>>>(A, a_src, a_dst, bg,
                                                       rowstart, cnt, csr, wsm, B, D, N);

    // SAGE1: GEMM reads B(hgat): P1 -> A, Q1 -> B (in-place). post: h1 -> B, D += w2*h1
    sage_gemm_kernel<<<(N + 63) / 64, 256, 0, stream>>>(B, W1hi, W1lo, b1, A, B, N);
    sage_post_kernel<<<(N + 3) / 4, 256, 0, stream>>>(A, B, rowstart, cnt, csr, wsm, 2, B, D, N);

    // SAGE2: GEMM reads B(h1): P2 -> A, Q2 -> B (in-place). post: D += w3*h2
    sage_gemm_kernel<<<(N + 63) / 64, 256, 0, stream>>>(B, W2hi, W2lo, b2, A, B, N);
    sage_post_kernel<<<(N + 3) / 4, 256, 0, stream>>>(A, B, rowstart, cnt, csr, wsm, 3, nullptr, D, N);

    link_pred_kernel<<<(EL + 15) / 16, 256, 0, stream>>>(eli, D, (float*)d_out, EL);
}

// Round 11
// 356.678 us; speedup vs baseline: 1.0297x; 1.0297x over previous
//
#include <hip/hip_runtime.h>
#include <math.h>
#include <float.h>

#define NEG_SLOPE 0.2f
#define NCHUNK 128   // edge-array chunks for the deterministic scatter

typedef short short8 __attribute__((ext_vector_type(8)));
typedef float f32x4  __attribute__((ext_vector_type(4)));

__device__ __forceinline__ unsigned short bf16hi(float x) {
    unsigned u = __float_as_uint(x);
    return (unsigned short)((u + 0x7FFFu + ((u >> 16) & 1u)) >> 16);
}
__device__ __forceinline__ float bf16tof(unsigned short h) {
    return __uint_as_float(((unsigned)h) << 16);
}

// K1: h = x @ W_gat (N x 11 @ 11 x 64) fp32, a_src/a_dst; blocks 0-7 also do
// weight prep (W1/W2 -> MFMA b-frag bf16 hi/lo) and block 0 softmax(alpha).
__global__ __launch_bounds__(256) void gat_input_kernel(
    const float* __restrict__ x, const float* __restrict__ Wg,
    const float* __restrict__ att_src, const float* __restrict__ att_dst,
    float* __restrict__ h, float* __restrict__ a_src, float* __restrict__ a_dst, int N,
    const float* __restrict__ W1l, const float* __restrict__ W1r,
    const float* __restrict__ W2l, const float* __restrict__ W2r,
    unsigned short* __restrict__ W1hi, unsigned short* __restrict__ W1lo,
    unsigned short* __restrict__ W2hi, unsigned short* __restrict__ W2lo,
    const float* __restrict__ alpha, float* __restrict__ wsm)
{
    if (blockIdx.x < 8) {
        if (blockIdx.x == 0 && threadIdx.x == 0) {
            float m = alpha[0];
            for (int i = 1; i < 4; i++) m = fmaxf(m, alpha[i]);
            float e[4], s = 0.f;
            for (int i = 0; i < 4; i++) { e[i] = expf(alpha[i] - m); s += e[i]; }
            for (int i = 0; i < 4; i++) wsm[i] = e[i] / s;
        }
        int which = blockIdx.x >> 2;
        const float* Wl = which ? W2l : W1l;
        const float* Wr = which ? W2r : W1r;
        unsigned short* Whi = which ? W2hi : W1hi;
        unsigned short* Wlo = which ? W2lo : W1lo;
        int idx = (blockIdx.x & 3) * 256 + threadIdx.x;
        int kc = idx >> 9, rem = idx & 511;
        int t = rem >> 6, ln = rem & 63;
        int quad = ln >> 4, col16 = ln & 15;
        int c = t * 16 + col16;
        #pragma unroll
        for (int j = 0; j < 8; j++) {
            int k = kc * 32 + quad * 8 + j;
            float w = (c < 64) ? Wl[k * 64 + c] : Wr[k * 64 + (c - 64)];
            unsigned short hi = bf16hi(w);
            unsigned short lo = bf16hi(w - bf16tof(hi));
            Whi[(size_t)idx * 8 + j] = hi;
            Wlo[(size_t)idx * 8 + j] = lo;
        }
    }
    __shared__ float Wl[11 * 64];
    int tid = threadIdx.x;
    for (int i = tid; i < 11 * 64; i += 256) Wl[i] = Wg[i];
    __syncthreads();
    int lane = tid & 63;
    int n = blockIdx.x * 4 + (tid >> 6);
    if (n >= N) return;
    float xv = (lane < 11) ? x[n * 11 + lane] : 0.f;
    float acc = 0.f;
    #pragma unroll
    for (int k = 0; k < 11; k++) acc += __shfl(xv, k, 64) * Wl[k * 64 + lane];
    h[(size_t)n * 64 + lane] = acc;
    float ps = acc * att_src[lane];
    float pd = acc * att_dst[lane];
    for (int off = 32; off; off >>= 1) {
        ps += __shfl_down(ps, off, 64);
        pd += __shfl_down(pd, off, 64);
    }
    if (lane == 0) { a_src[n] = ps; a_dst[n] = pd; }
}

// ---- Chunked CSR construction (bucket = dst >> 7; no global atomics) ----
// ebuf entry packed: (src << 7) | (dst & 127)

__global__ __launch_bounds__(1024) void edge_hist_kernel(
    const int* __restrict__ dst, int* __restrict__ hist, int E, int NBK)
{
    __shared__ int c[1024];
    int t = threadIdx.x;
    c[t] = 0;
    __syncthreads();
    int chunk = (E + NCHUNK - 1) / NCHUNK;
    int lo = blockIdx.x * chunk;
    int hi = lo + chunk; if (hi > E) hi = E;
    for (int i = lo + t; i < hi; i += 1024)
        atomicAdd(&c[dst[i] >> 7], 1);
    __syncthreads();
    if (t < NBK) hist[t * NCHUNK + blockIdx.x] = c[t];
}

__global__ __launch_bounds__(1024) void edge_scatter_kernel(
    const int* __restrict__ src, const int* __restrict__ dst,
    const int* __restrict__ rstart, unsigned* __restrict__ ebuf, int E, int NBK)
{
    __shared__ int cur[1024];
    int t = threadIdx.x;
    if (t < NBK) cur[t] = rstart[t * NCHUNK + blockIdx.x];
    __syncthreads();
    int chunk = (E + NCHUNK - 1) / NCHUNK;
    int lo = blockIdx.x * chunk;
    int hi = lo + chunk; if (hi > E) hi = E;
    for (int i = lo + t; i < hi; i += 1024) {
        int d = dst[i];
        int p = atomicAdd(&cur[d >> 7], 1);
        ebuf[p] = ((unsigned)src[i] << 7) | (unsigned)(d & 127);
    }
}

// ---- generic exclusive scan ----
__global__ __launch_bounds__(256) void scan_reduce_kernel(
    const int* __restrict__ v, int* __restrict__ bsum, int M)
{
    __shared__ int s[256];
    int t = threadIdx.x;
    int base = blockIdx.x * 1024 + t * 4;
    int sum = 0;
    #pragma unroll
    for (int j = 0; j < 4; j++) { int idx = base + j; if (idx < M) sum += v[idx]; }
    s[t] = sum; __syncthreads();
    for (int off = 128; off; off >>= 1) {
        if (t < off) s[t] += s[t + off];
        __syncthreads();
    }
    if (t == 0) bsum[blockIdx.x] = s[0];
}

__global__ __launch_bounds__(256) void scan_spine_kernel(
    const int* __restrict__ bsum, int* __restrict__ boff, int NB)
{
    __shared__ int s[256];
    int t = threadIdx.x;
    int v = (t < NB) ? bsum[t] : 0;
    s[t] = v; __syncthreads();
    for (int off = 1; off < 256; off <<= 1) {
        int x = (t >= off) ? s[t - off] : 0;
        __syncthreads();
        s[t] += x;
        __syncthreads();
    }
    if (t < NB) boff[t] = s[t] - v;
}

__global__ __launch_bounds__(256) void scan_apply_kernel(
    const int* __restrict__ v, const int* __restrict__ boff,
    int* __restrict__ out, int M)
{
    __shared__ int s[256];
    int t = threadIdx.x;
    int base = blockIdx.x * 1024;
    int vv[4]; int sum = 0;
    #pragma unroll
    for (int j = 0; j < 4; j++) {
        int idx = base + t * 4 + j;
        vv[j] = (idx < M) ? v[idx] : 0;
        sum += vv[j];
    }
    s[t] = sum; __syncthreads();
    for (int off = 1; off < 256; off <<= 1) {
        int x = (t >= off) ? s[t - off] : 0;
        __syncthreads();
        s[t] += x;
        __syncthreads();
    }
    int ex = s[t] - sum + boff[blockIdx.x];
    #pragma unroll
    for (int j = 0; j < 4; j++) {
        int idx = base + t * 4 + j;
        if (idx < M) out[idx] = ex;
        ex += vv[j];
    }
}

// one workgroup per bucket: LDS per-dst counts -> LDS scan -> cnt/rowstart -> scatter csr
__global__ __launch_bounds__(256) void bucket_build_kernel(
    const unsigned* __restrict__ ebuf, const int* __restrict__ rstart,
    int* __restrict__ cnt, int* __restrict__ rowstart,
    int* __restrict__ csr, int E, int N, int NBK)
{
    __shared__ int c[128];
    __shared__ int rs[128];
    __shared__ int cur[128];
    int b = blockIdx.x, t = threadIdx.x;
    if (t < 128) { c[t] = 0; cur[t] = 0; }
    __syncthreads();
    int beg = rstart[b * NCHUNK];
    int end = (b == NBK - 1) ? E : rstart[(b + 1) * NCHUNK];
    int n = end - beg;
    for (int j = t; j < n; j += 256)
        atomicAdd(&c[ebuf[beg + j] & 127u], 1);
    __syncthreads();
    int myc = (t < 128) ? c[t] : 0;
    if (t < 128) rs[t] = myc;
    __syncthreads();
    for (int off = 1; off < 128; off <<= 1) {
        int v = (t < 128 && t >= off) ? rs[t - off] : 0;
        __syncthreads();
        if (t < 128) rs[t] += v;
        __syncthreads();
    }
    int ex = (t < 128) ? (rs[t] - myc) : 0;
    __syncthreads();
    if (t < 128) rs[t] = ex;
    int base = b << 7;
    if (t < 128 && base + t < N) {
        cnt[base + t] = myc;
        rowstart[base + t] = beg + ex;
    }
    __syncthreads();
    for (int j = t; j < n; j += 256) {
        unsigned e = ebuf[beg + j];
        int d = (int)(e & 127u);
        int p = atomicAdd(&cur[d], 1);
        csr[beg + rs[d] + p] = (int)(e >> 7);
    }
}

// K2: GAT gather — 4 dst nodes per wave, 16 lanes (one 256B row) per node.
// Each lane owns its channel slice over ALL edges: no channel reduction.
__global__ __launch_bounds__(256) void gat_gather_kernel(
    const float* __restrict__ h, const float* __restrict__ a_src,
    const float* __restrict__ a_dst, const float* __restrict__ bg,
    const int* __restrict__ rowstart, const int* __restrict__ cnt,
    const int* __restrict__ csr, const float* __restrict__ wsm,
    float* __restrict__ hgat, float* __restrict__ outD, int N)
{
    const float4* __restrict__ h4 = (const float4*)h;
    int tid = threadIdx.x;
    int lane = tid & 63;
    int g = lane >> 4, sub = lane & 15;
    int gl = g << 4;
    int d = blockIdx.x * 16 + (tid >> 6) * 4 + g;
    if (d >= N) return;   // group-uniform exit (all 16 lanes share d)
    float ad = a_dst[d];
    int beg = rowstart[d], deg = cnt[d];
    float a0 = a_src[d] + ad;
    float lg0 = a0 > 0.f ? a0 : NEG_SLOPE * a0;
    float w_self = expf(lg0);
    float4 acc = h4[(size_t)d * 16 + sub];
    acc.x *= w_self; acc.y *= w_self; acc.z *= w_self; acc.w *= w_self;
    float l_lane = 0.f;
    for (int base = 0; base < deg; base += 16) {
        int nv = deg - base; if (nv > 16) nv = 16;
        int sid = (sub < nv) ? csr[beg + base + sub] : 0;
        float aa = a_src[sid] + ad;
        float lg = aa > 0.f ? aa : NEG_SLOPE * aa;
        float w = (sub < nv) ? expf(lg) : 0.f;
        l_lane += w;
        for (int j = 0; j < nv; j += 4) {
            int   i0 = __shfl(sid, gl + j,     64); float w0 = __shfl(w, gl + j,     64);
            int   i1 = __shfl(sid, gl + j + 1, 64); float w1 = __shfl(w, gl + j + 1, 64);
            int   i2 = __shfl(sid, gl + j + 2, 64); float w2 = __shfl(w, gl + j + 2, 64);
            int   i3 = __shfl(sid, gl + j + 3, 64); float w3 = __shfl(w, gl + j + 3, 64);
            {   float4 v = h4[(size_t)i0 * 16 + sub];
                acc.x += w0 * v.x; acc.y += w0 * v.y; acc.z += w0 * v.z; acc.w += w0 * v.w; }
            if (j + 1 < nv) { float4 v = h4[(size_t)i1 * 16 + sub];
                acc.x += w1 * v.x; acc.y += w1 * v.y; acc.z += w1 * v.z; acc.w += w1 * v.w; }
            if (j + 2 < nv) { float4 v = h4[(size_t)i2 * 16 + sub];
                acc.x += w2 * v.x; acc.y += w2 * v.y; acc.z += w2 * v.z; acc.w += w2 * v.w; }
            if (j + 3 < nv) { float4 v = h4[(size_t)i3 * 16 + sub];
                acc.x += w3 * v.x; acc.y += w3 * v.y; acc.z += w3 * v.z; acc.w += w3 * v.w; }
        }
    }
    // denominator: reduce within the 16-lane group only
    #pragma unroll
    for (int off = 1; off < 16; off <<= 1) l_lane += __shfl_xor(l_lane, off, 64);
    float l = l_lane + w_self;
    float inv = 1.0f / (l + 1e-16f);
    float4 bb = ((const float4*)bg)[sub];
    float4 out;
    out.x = acc.x * inv + bb.x; out.y = acc.y * inv + bb.y;
    out.z = acc.z * inv + bb.z; out.w = acc.w * inv + bb.w;
    size_t idx = (size_t)d * 16 + sub;
    ((float4*)hgat)[idx] = out;
    float w0 = wsm[0];
    float4 o; o.x = w0 * out.x; o.y = w0 * out.y; o.z = w0 * out.z; o.w = w0 * out.w;
    ((float4*)outD)[idx] = o;
}

// K6: dense GEMM [P|Q] = hin @ [Wl|Wr] (+b on Q half) via mfma 16x16x32 bf16x3.
__global__ __launch_bounds__(256) void sage_gemm_kernel(
    const float* __restrict__ hin,
    const unsigned short* __restrict__ Whi, const unsigned short* __restrict__ Wlo,
    const float* __restrict__ bvec,
    float* __restrict__ P, float* __restrict__ Q, int N)
{
    int wave = threadIdx.x >> 6, lane = threadIdx.x & 63;
    int base = blockIdx.x * 64 + wave * 16;
    if (base >= N) return;
    int quad = lane >> 4, col16 = lane & 15;
    int m = base + col16;
    int mc = m < N ? m : N - 1;
    f32x4 acc[8];
    #pragma unroll
    for (int t = 0; t < 8; t++) acc[t] = (f32x4){0.f, 0.f, 0.f, 0.f};
    #pragma unroll
    for (int kc = 0; kc < 2; kc++) {
        const float* ap = hin + (size_t)mc * 64 + kc * 32 + quad * 8;
        float4 va = *(const float4*)ap;
        float4 vb = *(const float4*)(ap + 4);
        float av[8] = {va.x, va.y, va.z, va.w, vb.x, vb.y, vb.z, vb.w};
        short8 ahi, alo;
        #pragma unroll
        for (int j = 0; j < 8; j++) {
            unsigned short hh = bf16hi(av[j]);
            ahi[j] = (short)hh;
            alo[j] = (short)bf16hi(av[j] - bf16tof(hh));
        }
        #pragma unroll
        for (int t = 0; t < 8; t++) {
            size_t off = ((size_t)(kc * 8 + t) * 64 + lane) * 8;
            short8 bhi = *(const short8*)(Whi + off);
            short8 blo = *(const short8*)(Wlo + off);
            acc[t] = __builtin_amdgcn_mfma_f32_16x16x32_bf16(ahi, bhi, acc[t], 0, 0, 0);
            acc[t] = __builtin_amdgcn_mfma_f32_16x16x32_bf16(alo, bhi, acc[t], 0, 0, 0);
            acc[t] = __builtin_amdgcn_mfma_f32_16x16x32_bf16(ahi, blo, acc[t], 0, 0, 0);
        }
    }
    #pragma unroll
    for (int t = 0; t < 8; t++) {
        #pragma unroll
        for (int r = 0; r < 4; r++) {
            int node = base + quad * 4 + r;
            if (node < N) {
                float v = acc[t][r];
                if (t < 4) {
                    P[(size_t)node * 64 + t * 16 + col16] = v;
                } else {
                    int c = (t - 4) * 16 + col16;
                    Q[(size_t)node * 64 + c] = v + bvec[c];
                }
            }
        }
    }
}

// K7: SAGE post — 4 dst nodes per wave, 16 lanes per node, no reductions.
// h' = mean_nbr(P) + Q[d]; outD += w*h'; optional hout store.
__global__ __launch_bounds__(256) void sage_post_kernel(
    const float* __restrict__ P, const float* __restrict__ Q,
    const int* __restrict__ rowstart, const int* __restrict__ cnt,
    const int* __restrict__ csr, const float* __restrict__ wsm, int widx,
    float* __restrict__ hout, float* __restrict__ outD, int N)
{
    const float4* __restrict__ P4 = (const float4*)P;
    int tid = threadIdx.x;
    int lane = tid & 63;
    int g = lane >> 4, sub = lane & 15;
    int gl = g << 4;
    int d = blockIdx.x * 16 + (tid >> 6) * 4 + g;
    if (d >= N) return;   // group-uniform
    int beg = rowstart[d], deg = cnt[d];
    float4 s0 = make_float4(0.f,0.f,0.f,0.f), s1 = s0, s2 = s0, s3 = s0;
    for (int base = 0; base < deg; base += 16) {
        int nv = deg - base; if (nv > 16) nv = 16;
        int sid = (sub < nv) ? csr[beg + base + sub] : 0;
        for (int j = 0; j < nv; j += 4) {
            int i0 = __shfl(sid, gl + j,     64);
            int i1 = __shfl(sid, gl + j + 1, 64);
            int i2 = __shfl(sid, gl + j + 2, 64);
            int i3 = __shfl(sid, gl + j + 3, 64);
            {   float4 v = P4[(size_t)i0 * 16 + sub];
                s0.x += v.x; s0.y += v.y; s0.z += v.z; s0.w += v.w; }
            if (j + 1 < nv) { float4 v = P4[(size_t)i1 * 16 + sub];
                s1.x += v.x; s1.y += v.y; s1.z += v.z; s1.w += v.w; }
            if (j + 2 < nv) { float4 v = P4[(size_t)i2 * 16 + sub];
                s2.x += v.x; s2.y += v.y; s2.z += v.z; s2.w += v.w; }
            if (j + 3 < nv) { float4 v = P4[(size_t)i3 * 16 + sub];
                s3.x += v.x; s3.y += v.y; s3.z += v.z; s3.w += v.w; }
        }
    }
    float4 sv;
    sv.x = (s0.x + s1.x) + (s2.x + s3.x);
    sv.y = (s0.y + s1.y) + (s2.y + s3.y);
    sv.z = (s0.z + s1.z) + (s2.z + s3.z);
    sv.w = (s0.w + s1.w) + (s2.w + s3.w);
    float invd = 1.0f / fmaxf((float)deg, 1.0f);
    size_t idx = (size_t)d * 16 + sub;
    float4 q4 = ((const float4*)Q)[idx];
    float4 o;
    o.x = sv.x * invd + q4.x; o.y = sv.y * invd + q4.y;
    o.z = sv.z * invd + q4.z; o.w = sv.w * invd + q4.w;
    if (hout) ((float4*)hout)[idx] = o;
    float w = wsm[widx];
    float4 dd = ((float4*)outD)[idx];
    dd.x += w * o.x; dd.y += w * o.y; dd.z += w * o.z; dd.w += w * o.w;
    ((float4*)outD)[idx] = dd;
}

// K8: 16 lanes per label-edge (float4 rows): out[e] = dot(outf[a], outf[b])
__global__ __launch_bounds__(256) void link_pred_kernel(
    const int* __restrict__ eli, const float* __restrict__ outf,
    float* __restrict__ out, int EL)
{
    const float4* __restrict__ o4 = (const float4*)outf;
    int e = blockIdx.x * 16 + (threadIdx.x >> 4);
    int sub = threadIdx.x & 15;
    if (e >= EL) return;
    int a = eli[e], b = eli[EL + e];
    float4 pa = o4[(size_t)a * 16 + sub];
    float4 pb = o4[(size_t)b * 16 + sub];
    float p = pa.x * pb.x + pa.y * pb.y + pa.z * pb.z + pa.w * pb.w;
    for (int off = 8; off; off >>= 1) p += __shfl_xor(p, off, 64);
    if (sub == 0) out[e] = p;
}

extern "C" void kernel_launch(void* const* d_in, const int* in_sizes, int n_in,
                              void* d_out, int out_size, void* d_ws, size_t ws_size,
                              hipStream_t stream)
{
    const float* x      = (const float*)d_in[0];
    const int*   ei     = (const int*)d_in[1];
    const int*   eli    = (const int*)d_in[2];
    const float* Wg     = (const float*)d_in[3];
    const float* att_s  = (const float*)d_in[4];
    const float* att_d  = (const float*)d_in[5];
    const float* bg     = (const float*)d_in[6];
    const float* W1l    = (const float*)d_in[7];
    const float* W1r    = (const float*)d_in[8];
    const float* b1     = (const float*)d_in[9];
    const float* W2l    = (const float*)d_in[10];
    const float* W2r    = (const float*)d_in[11];
    const float* b2     = (const float*)d_in[12];
    const float* alpha  = (const float*)d_in[13];

    const int N  = in_sizes[0] / 11;
    const int E  = in_sizes[1] / 2;
    const int EL = in_sizes[2] / 2;
    const int NBK = (N + 127) >> 7;
    const int M   = NBK * NCHUNK;

    const int* src = ei;
    const int* dst = ei + E;

    // workspace layout
    float* A        = (float*)d_ws;              // N*64: h -> P1 -> P2
    float* B        = A + (size_t)N * 64;        // N*64: h_gat -> Q1/h1 -> Q2
    float* D        = B + (size_t)N * 64;        // N*64: ebuf (CSR build) then output accum
    float* a_src    = D + (size_t)N * 64;        // N
    float* a_dst    = a_src + N;                 // N
    int*   cnt      = (int*)(a_dst + N);         // N
    int*   rowstart = cnt + N;                   // N
    int*   hist     = rowstart + N;              // M
    int*   rstart   = hist + M;                  // M
    int*   bsum     = rstart + M;                // 256
    int*   boff     = bsum + 256;                // 256
    int*   csr      = boff + 256;                // E
    unsigned short* wf = (unsigned short*)(csr + E);
    unsigned short* W1hi = wf;
    unsigned short* W1lo = wf + 8192;
    unsigned short* W2hi = wf + 16384;
    unsigned short* W2lo = wf + 24576;
    float* wsm      = (float*)(wf + 32768);      // 4
    unsigned* ebuf  = (unsigned*)D;

    gat_input_kernel<<<(N + 3) / 4, 256, 0, stream>>>(x, Wg, att_s, att_d, A, a_src, a_dst, N,
                                                      W1l, W1r, W2l, W2r,
                                                      W1hi, W1lo, W2hi, W2lo, alpha, wsm);

    edge_hist_kernel<<<NCHUNK, 1024, 0, stream>>>(dst, hist, E, NBK);
    int NB = (M + 1023) / 1024;
    scan_reduce_kernel<<<NB, 256, 0, stream>>>(hist, bsum, M);
    scan_spine_kernel<<<1, 256, 0, stream>>>(bsum, boff, NB);
    scan_apply_kernel<<<NB, 256, 0, stream>>>(hist, boff, rstart, M);
    edge_scatter_kernel<<<NCHUNK, 1024, 0, stream>>>(src, dst, rstart, ebuf, E, NBK);
    bucket_build_kernel<<<NBK, 256, 0, stream>>>(ebuf, rstart, cnt, rowstart, csr, E, N, NBK);

    gat_gather_kernel<<<(N + 15) / 16, 256, 0, stream>>>(A, a_src, a_dst, bg,
                                                         rowstart, cnt, csr, wsm, B, D, N);

    sage_gemm_kernel<<<(N + 63) / 64, 256, 0, stream>>>(B, W1hi, W1lo, b1, A, B, N);
    sage_post_kernel<<<(N + 15) / 16, 256, 0, stream>>>(A, B, rowstart, cnt, csr, wsm, 2, B, D, N);

    sage_gemm_kernel<<<(N + 63) / 64, 256, 0, stream>>>(B, W2hi, W2lo, b2, A, B, N);
    sage_post_kernel<<<(N + 15) / 16, 256, 0, stream>>>(A, B, rowstart, cnt, csr, wsm, 3, nullptr, D, N);

    link_pred_kernel<<<(EL + 15) / 16, 256, 0, stream>>>(eli, D, (float*)d_out, EL);
}

// Round 12
// 350.740 us; speedup vs baseline: 1.0471x; 1.0169x over previous
//
#include <hip/hip_runtime.h>
#include <math.h>
#include <float.h>

#define NEG_SLOPE 0.2f
#define NCHUNK 128   // edge-array chunks for the deterministic scatter

typedef short short8 __attribute__((ext_vector_type(8)));
typedef float f32x4  __attribute__((ext_vector_type(4)));

__device__ __forceinline__ unsigned short bf16hi(float x) {
    unsigned u = __float_as_uint(x);
    return (unsigned short)((u + 0x7FFFu + ((u >> 16) & 1u)) >> 16);
}
__device__ __forceinline__ float bf16tof(unsigned short h) {
    return __uint_as_float(((unsigned)h) << 16);
}

// K1: h = x @ W_gat (N x 11 @ 11 x 64) fp32, a_src/a_dst; blocks 0-7 also do
// weight prep; block 8 zeroes sentinel row N and sets a_src[N] = -1e30.
__global__ __launch_bounds__(256) void gat_input_kernel(
    const float* __restrict__ x, const float* __restrict__ Wg,
    const float* __restrict__ att_src, const float* __restrict__ att_dst,
    float* __restrict__ h, float* __restrict__ a_src, float* __restrict__ a_dst, int N,
    const float* __restrict__ W1l, const float* __restrict__ W1r,
    const float* __restrict__ W2l, const float* __restrict__ W2r,
    unsigned short* __restrict__ W1hi, unsigned short* __restrict__ W1lo,
    unsigned short* __restrict__ W2hi, unsigned short* __restrict__ W2lo,
    const float* __restrict__ alpha, float* __restrict__ wsm)
{
    if (blockIdx.x < 8) {
        if (blockIdx.x == 0 && threadIdx.x == 0) {
            float m = alpha[0];
            for (int i = 1; i < 4; i++) m = fmaxf(m, alpha[i]);
            float e[4], s = 0.f;
            for (int i = 0; i < 4; i++) { e[i] = expf(alpha[i] - m); s += e[i]; }
            for (int i = 0; i < 4; i++) wsm[i] = e[i] / s;
        }
        int which = blockIdx.x >> 2;
        const float* Wl = which ? W2l : W1l;
        const float* Wr = which ? W2r : W1r;
        unsigned short* Whi = which ? W2hi : W1hi;
        unsigned short* Wlo = which ? W2lo : W1lo;
        int idx = (blockIdx.x & 3) * 256 + threadIdx.x;
        int kc = idx >> 9, rem = idx & 511;
        int t = rem >> 6, ln = rem & 63;
        int quad = ln >> 4, col16 = ln & 15;
        int c = t * 16 + col16;
        #pragma unroll
        for (int j = 0; j < 8; j++) {
            int k = kc * 32 + quad * 8 + j;
            float w = (c < 64) ? Wl[k * 64 + c] : Wr[k * 64 + (c - 64)];
            unsigned short hi = bf16hi(w);
            unsigned short lo = bf16hi(w - bf16tof(hi));
            Whi[(size_t)idx * 8 + j] = hi;
            Wlo[(size_t)idx * 8 + j] = lo;
        }
    } else if (blockIdx.x == 8) {
        // sentinel row N: h=0, a_src=-1e30 (pad edges get exp() = 0)
        if (threadIdx.x < 64) h[(size_t)N * 64 + threadIdx.x] = 0.f;
        if (threadIdx.x == 64) a_src[N] = -1e30f;
    }
    __shared__ float Wl[11 * 64];
    int tid = threadIdx.x;
    for (int i = tid; i < 11 * 64; i += 256) Wl[i] = Wg[i];
    __syncthreads();
    int lane = tid & 63;
    int n = blockIdx.x * 4 + (tid >> 6);
    if (n >= N) return;
    float xv = (lane < 11) ? x[n * 11 + lane] : 0.f;
    float acc = 0.f;
    #pragma unroll
    for (int k = 0; k < 11; k++) acc += __shfl(xv, k, 64) * Wl[k * 64 + lane];
    h[(size_t)n * 64 + lane] = acc;
    float ps = acc * att_src[lane];
    float pd = acc * att_dst[lane];
    for (int off = 32; off; off >>= 1) {
        ps += __shfl_down(ps, off, 64);
        pd += __shfl_down(pd, off, 64);
    }
    if (lane == 0) { a_src[n] = ps; a_dst[n] = pd; }
}

// ---- Chunked CSR construction (bucket = dst >> 7; no global atomics) ----
// ebuf entry packed: (src << 7) | (dst & 127). csr rows padded to mult of 4
// with sentinel src = N; per-bucket csr region = raw start + 384*b slack.

__global__ __launch_bounds__(1024) void edge_hist_kernel(
    const int* __restrict__ dst, int* __restrict__ hist, int E, int NBK)
{
    __shared__ int c[1024];
    int t = threadIdx.x;
    c[t] = 0;
    __syncthreads();
    int chunk = (E + NCHUNK - 1) / NCHUNK;
    int lo = blockIdx.x * chunk;
    int hi = lo + chunk; if (hi > E) hi = E;
    for (int i = lo + t; i < hi; i += 1024)
        atomicAdd(&c[dst[i] >> 7], 1);
    __syncthreads();
    if (t < NBK) hist[t * NCHUNK + blockIdx.x] = c[t];
}

__global__ __launch_bounds__(1024) void edge_scatter_kernel(
    const int* __restrict__ src, const int* __restrict__ dst,
    const int* __restrict__ rstart, unsigned* __restrict__ ebuf, int E, int NBK)
{
    __shared__ int cur[1024];
    int t = threadIdx.x;
    if (t < NBK) cur[t] = rstart[t * NCHUNK + blockIdx.x];
    __syncthreads();
    int chunk = (E + NCHUNK - 1) / NCHUNK;
    int lo = blockIdx.x * chunk;
    int hi = lo + chunk; if (hi > E) hi = E;
    for (int i = lo + t; i < hi; i += 1024) {
        int d = dst[i];
        int p = atomicAdd(&cur[d >> 7], 1);
        ebuf[p] = ((unsigned)src[i] << 7) | (unsigned)(d & 127);
    }
}

// ---- generic exclusive scan ----
__global__ __launch_bounds__(256) void scan_reduce_kernel(
    const int* __restrict__ v, int* __restrict__ bsum, int M)
{
    __shared__ int s[256];
    int t = threadIdx.x;
    int base = blockIdx.x * 1024 + t * 4;
    int sum = 0;
    #pragma unroll
    for (int j = 0; j < 4; j++) { int idx = base + j; if (idx < M) sum += v[idx]; }
    s[t] = sum; __syncthreads();
    for (int off = 128; off; off >>= 1) {
        if (t < off) s[t] += s[t + off];
        __syncthreads();
    }
    if (t == 0) bsum[blockIdx.x] = s[0];
}

__global__ __launch_bounds__(256) void scan_spine_kernel(
    const int* __restrict__ bsum, int* __restrict__ boff, int NB)
{
    __shared__ int s[256];
    int t = threadIdx.x;
    int v = (t < NB) ? bsum[t] : 0;
    s[t] = v; __syncthreads();
    for (int off = 1; off < 256; off <<= 1) {
        int x = (t >= off) ? s[t - off] : 0;
        __syncthreads();
        s[t] += x;
        __syncthreads();
    }
    if (t < NB) boff[t] = s[t] - v;
}

__global__ __launch_bounds__(256) void scan_apply_kernel(
    const int* __restrict__ v, const int* __restrict__ boff,
    int* __restrict__ out, int M)
{
    __shared__ int s[256];
    int t = threadIdx.x;
    int base = blockIdx.x * 1024;
    int vv[4]; int sum = 0;
    #pragma unroll
    for (int j = 0; j < 4; j++) {
        int idx = base + t * 4 + j;
        vv[j] = (idx < M) ? v[idx] : 0;
        sum += vv[j];
    }
    s[t] = sum; __syncthreads();
    for (int off = 1; off < 256; off <<= 1) {
        int x = (t >= off) ? s[t - off] : 0;
        __syncthreads();
        s[t] += x;
        __syncthreads();
    }
    int ex = s[t] - sum + boff[blockIdx.x];
    #pragma unroll
    for (int j = 0; j < 4; j++) {
        int idx = base + t * 4 + j;
        if (idx < M) out[idx] = ex;
        ex += vv[j];
    }
}

// one workgroup per bucket: LDS per-dst counts -> padded LDS scan -> cnt/rowstart
// -> scatter csr + write pad slots (src = N)
__global__ __launch_bounds__(256) void bucket_build_kernel(
    const unsigned* __restrict__ ebuf, const int* __restrict__ rstart,
    int* __restrict__ cnt, int* __restrict__ rowstart,
    int* __restrict__ csr, int E, int N, int NBK)
{
    __shared__ int c[128];
    __shared__ int rs[128];
    __shared__ int cur[128];
    int b = blockIdx.x, t = threadIdx.x;
    if (t < 128) { c[t] = 0; cur[t] = 0; }
    __syncthreads();
    int beg = rstart[b * NCHUNK];
    int end = (b == NBK - 1) ? E : rstart[(b + 1) * NCHUNK];
    int n = end - beg;
    int pbeg = beg + 384 * b;   // padded csr base for this bucket
    for (int j = t; j < n; j += 256)
        atomicAdd(&c[ebuf[beg + j] & 127u], 1);
    __syncthreads();
    int myc = (t < 128) ? c[t] : 0;
    int mypc = (myc + 3) & ~3;          // padded count
    if (t < 128) rs[t] = mypc;
    __syncthreads();
    for (int off = 1; off < 128; off <<= 1) {
        int v = (t < 128 && t >= off) ? rs[t - off] : 0;
        __syncthreads();
        if (t < 128) rs[t] += v;
        __syncthreads();
    }
    int ex = (t < 128) ? (rs[t] - mypc) : 0;
    __syncthreads();
    if (t < 128) rs[t] = ex;
    int base = b << 7;
    if (t < 128 && base + t < N) {
        cnt[base + t] = myc;
        rowstart[base + t] = pbeg + ex;
    }
    __syncthreads();
    for (int j = t; j < n; j += 256) {
        unsigned e = ebuf[beg + j];
        int d = (int)(e & 127u);
        int p = atomicAdd(&cur[d], 1);
        csr[pbeg + rs[d] + p] = (int)(e >> 7);
    }
    __syncthreads();
    if (t < 128) {
        for (int k = myc; k < mypc; k++) csr[pbeg + rs[t] + k] = N;  // pads
    }
}

// K2: GAT gather — 4 dst nodes per wave, 16 lanes per node, branch-free
// 4-wide unrolled float4 loads (rows padded; sentinel row N has weight 0).
__global__ __launch_bounds__(256) void gat_gather_kernel(
    const float* __restrict__ h, const float* __restrict__ a_src,
    const float* __restrict__ a_dst, const float* __restrict__ bg,
    const int* __restrict__ rowstart, const int* __restrict__ cnt,
    const int* __restrict__ csr, const float* __restrict__ wsm,
    float* __restrict__ hgat, float* __restrict__ outD, int N)
{
    const float4* __restrict__ h4 = (const float4*)h;
    int tid = threadIdx.x;
    int lane = tid & 63;
    int g = lane >> 4, sub = lane & 15;
    int gl = g << 4;
    int d = blockIdx.x * 16 + (tid >> 6) * 4 + g;
    if (d >= N) return;   // group-uniform
    float ad = a_dst[d];
    int beg = rowstart[d], deg = cnt[d];
    int degp = (deg + 3) & ~3;
    float a0 = a_src[d] + ad;
    float lg0 = a0 > 0.f ? a0 : NEG_SLOPE * a0;
    float w_self = expf(lg0);
    float4 acc = h4[(size_t)d * 16 + sub];
    acc.x *= w_self; acc.y *= w_self; acc.z *= w_self; acc.w *= w_self;
    float l_lane = 0.f;
    for (int base = 0; base < degp; base += 16) {
        int nvc = degp - base; if (nvc > 16) nvc = 16;   // multiple of 4
        int sid = (sub < nvc) ? csr[beg + base + sub] : N;
        float aa = a_src[sid] + ad;
        float lg = aa > 0.f ? aa : NEG_SLOPE * aa;
        float w = expf(lg);   // 0 for sentinel/pad lanes
        l_lane += w;
        for (int j = 0; j < nvc; j += 4) {
            int   i0 = __shfl(sid, gl + j,     64); float w0 = __shfl(w, gl + j,     64);
            int   i1 = __shfl(sid, gl + j + 1, 64); float w1 = __shfl(w, gl + j + 1, 64);
            int   i2 = __shfl(sid, gl + j + 2, 64); float w2 = __shfl(w, gl + j + 2, 64);
            int   i3 = __shfl(sid, gl + j + 3, 64); float w3 = __shfl(w, gl + j + 3, 64);
            float4 v0 = h4[(size_t)i0 * 16 + sub];
            float4 v1 = h4[(size_t)i1 * 16 + sub];
            float4 v2 = h4[(size_t)i2 * 16 + sub];
            float4 v3 = h4[(size_t)i3 * 16 + sub];
            acc.x += w0 * v0.x + w1 * v1.x + w2 * v2.x + w3 * v3.x;
            acc.y += w0 * v0.y + w1 * v1.y + w2 * v2.y + w3 * v3.y;
            acc.z += w0 * v0.z + w1 * v1.z + w2 * v2.z + w3 * v3.z;
            acc.w += w0 * v0.w + w1 * v1.w + w2 * v2.w + w3 * v3.w;
        }
    }
    #pragma unroll
    for (int off = 1; off < 16; off <<= 1) l_lane += __shfl_xor(l_lane, off, 64);
    float l = l_lane + w_self;
    float inv = 1.0f / (l + 1e-16f);
    float4 bb = ((const float4*)bg)[sub];
    float4 out;
    out.x = acc.x * inv + bb.x; out.y = acc.y * inv + bb.y;
    out.z = acc.z * inv + bb.z; out.w = acc.w * inv + bb.w;
    size_t idx = (size_t)d * 16 + sub;
    ((float4*)hgat)[idx] = out;
    float w0 = wsm[0];
    float4 o; o.x = w0 * out.x; o.y = w0 * out.y; o.z = w0 * out.z; o.w = w0 * out.w;
    ((float4*)outD)[idx] = o;
}

// K6: dense GEMM [P|Q] = hin @ [Wl|Wr] (+b on Q half) via mfma 16x16x32 bf16x3.
__global__ __launch_bounds__(256) void sage_gemm_kernel(
    const float* __restrict__ hin,
    const unsigned short* __restrict__ Whi, const unsigned short* __restrict__ Wlo,
    const float* __restrict__ bvec,
    float* __restrict__ P, float* __restrict__ Q, int N)
{
    int wave = threadIdx.x >> 6, lane = threadIdx.x & 63;
    int base = blockIdx.x * 64 + wave * 16;
    if (base >= N) return;
    int quad = lane >> 4, col16 = lane & 15;
    int m = base + col16;
    int mc = m < N ? m : N - 1;
    f32x4 acc[8];
    #pragma unroll
    for (int t = 0; t < 8; t++) acc[t] = (f32x4){0.f, 0.f, 0.f, 0.f};
    #pragma unroll
    for (int kc = 0; kc < 2; kc++) {
        const float* ap = hin + (size_t)mc * 64 + kc * 32 + quad * 8;
        float4 va = *(const float4*)ap;
        float4 vb = *(const float4*)(ap + 4);
        float av[8] = {va.x, va.y, va.z, va.w, vb.x, vb.y, vb.z, vb.w};
        short8 ahi, alo;
        #pragma unroll
        for (int j = 0; j < 8; j++) {
            unsigned short hh = bf16hi(av[j]);
            ahi[j] = (short)hh;
            alo[j] = (short)bf16hi(av[j] - bf16tof(hh));
        }
        #pragma unroll
        for (int t = 0; t < 8; t++) {
            size_t off = ((size_t)(kc * 8 + t) * 64 + lane) * 8;
            short8 bhi = *(const short8*)(Whi + off);
            short8 blo = *(const short8*)(Wlo + off);
            acc[t] = __builtin_amdgcn_mfma_f32_16x16x32_bf16(ahi, bhi, acc[t], 0, 0, 0);
            acc[t] = __builtin_amdgcn_mfma_f32_16x16x32_bf16(alo, bhi, acc[t], 0, 0, 0);
            acc[t] = __builtin_amdgcn_mfma_f32_16x16x32_bf16(ahi, blo, acc[t], 0, 0, 0);
        }
    }
    #pragma unroll
    for (int t = 0; t < 8; t++) {
        #pragma unroll
        for (int r = 0; r < 4; r++) {
            int node = base + quad * 4 + r;
            if (node < N) {
                float v = acc[t][r];
                if (t < 4) {
                    P[(size_t)node * 64 + t * 16 + col16] = v;
                } else {
                    int c = (t - 4) * 16 + col16;
                    Q[(size_t)node * 64 + c] = v + bvec[c];
                }
            }
        }
    }
}

// K7: SAGE post — 4 dst nodes per wave, 16 lanes per node, branch-free loads
// (pads -> zero row N). h' = mean_nbr(P) + Q[d]; outD += w*h'.
__global__ __launch_bounds__(256) void sage_post_kernel(
    const float* __restrict__ P, const float* __restrict__ Q,
    const int* __restrict__ rowstart, const int* __restrict__ cnt,
    const int* __restrict__ csr, const float* __restrict__ wsm, int widx,
    float* __restrict__ hout, float* __restrict__ outD, int N)
{
    const float4* __restrict__ P4 = (const float4*)P;
    int tid = threadIdx.x;
    int lane = tid & 63;
    int g = lane >> 4, sub = lane & 15;
    int gl = g << 4;
    int d = blockIdx.x * 16 + (tid >> 6) * 4 + g;
    if (d >= N) return;   // group-uniform
    int beg = rowstart[d], deg = cnt[d];
    int degp = (deg + 3) & ~3;
    float4 s0 = make_float4(0.f,0.f,0.f,0.f), s1 = s0, s2 = s0, s3 = s0;
    for (int base = 0; base < degp; base += 16) {
        int nvc = degp - base; if (nvc > 16) nvc = 16;
        int sid = (sub < nvc) ? csr[beg + base + sub] : N;
        for (int j = 0; j < nvc; j += 4) {
            int i0 = __shfl(sid, gl + j,     64);
            int i1 = __shfl(sid, gl + j + 1, 64);
            int i2 = __shfl(sid, gl + j + 2, 64);
            int i3 = __shfl(sid, gl + j + 3, 64);
            float4 v0 = P4[(size_t)i0 * 16 + sub];
            float4 v1 = P4[(size_t)i1 * 16 + sub];
            float4 v2 = P4[(size_t)i2 * 16 + sub];
            float4 v3 = P4[(size_t)i3 * 16 + sub];
            s0.x += v0.x; s0.y += v0.y; s0.z += v0.z; s0.w += v0.w;
            s1.x += v1.x; s1.y += v1.y; s1.z += v1.z; s1.w += v1.w;
            s2.x += v2.x; s2.y += v2.y; s2.z += v2.z; s2.w += v2.w;
            s3.x += v3.x; s3.y += v3.y; s3.z += v3.z; s3.w += v3.w;
        }
    }
    float4 sv;
    sv.x = (s0.x + s1.x) + (s2.x + s3.x);
    sv.y = (s0.y + s1.y) + (s2.y + s3.y);
    sv.z = (s0.z + s1.z) + (s2.z + s3.z);
    sv.w = (s0.w + s1.w) + (s2.w + s3.w);
    float invd = 1.0f / fmaxf((float)deg, 1.0f);
    size_t idx = (size_t)d * 16 + sub;
    float4 q4 = ((const float4*)Q)[idx];
    float4 o;
    o.x = sv.x * invd + q4.x; o.y = sv.y * invd + q4.y;
    o.z = sv.z * invd + q4.z; o.w = sv.w * invd + q4.w;
    if (hout) ((float4*)hout)[idx] = o;
    float w = wsm[widx];
    float4 dd = ((float4*)outD)[idx];
    dd.x += w * o.x; dd.y += w * o.y; dd.z += w * o.z; dd.w += w * o.w;
    ((float4*)outD)[idx] = dd;
}

// K8: 16 lanes per label-edge (float4 rows): out[e] = dot(outf[a], outf[b])
__global__ __launch_bounds__(256) void link_pred_kernel(
    const int* __restrict__ eli, const float* __restrict__ outf,
    float* __restrict__ out, int EL)
{
    const float4* __restrict__ o4 = (const float4*)outf;
    int e = blockIdx.x * 16 + (threadIdx.x >> 4);
    int sub = threadIdx.x & 15;
    if (e >= EL) return;
    int a = eli[e], b = eli[EL + e];
    float4 pa = o4[(size_t)a * 16 + sub];
    float4 pb = o4[(size_t)b * 16 + sub];
    float p = pa.x * pb.x + pa.y * pb.y + pa.z * pb.z + pa.w * pb.w;
    for (int off = 8; off; off >>= 1) p += __shfl_xor(p, off, 64);
    if (sub == 0) out[e] = p;
}

extern "C" void kernel_launch(void* const* d_in, const int* in_sizes, int n_in,
                              void* d_out, int out_size, void* d_ws, size_t ws_size,
                              hipStream_t stream)
{
    const float* x      = (const float*)d_in[0];
    const int*   ei     = (const int*)d_in[1];
    const int*   eli    = (const int*)d_in[2];
    const float* Wg     = (const float*)d_in[3];
    const float* att_s  = (const float*)d_in[4];
    const float* att_d  = (const float*)d_in[5];
    const float* bg     = (const float*)d_in[6];
    const float* W1l    = (const float*)d_in[7];
    const float* W1r    = (const float*)d_in[8];
    const float* b1     = (const float*)d_in[9];
    const float* W2l    = (const float*)d_in[10];
    const float* W2r    = (const float*)d_in[11];
    const float* b2     = (const float*)d_in[12];
    const float* alpha  = (const float*)d_in[13];

    const int N  = in_sizes[0] / 11;
    const int E  = in_sizes[1] / 2;
    const int EL = in_sizes[2] / 2;
    const int NBK = (N + 127) >> 7;
    const int M   = NBK * NCHUNK;
    const int CSRSZ = E + 384 * NBK;   // padded csr capacity

    const int* src = ei;
    const int* dst = ei + E;

    // workspace layout (A/B have a sentinel row N)
    float* A        = (float*)d_ws;                    // (N+1)*64: h -> P1 -> P2 (row N = 0)
    float* B        = A + (size_t)(N + 1) * 64;        // (N+1)*64: hgat -> Q1/h1 -> Q2
    float* D        = B + (size_t)(N + 1) * 64;        // N*64: ebuf (CSR build) then output accum
    float* a_src    = D + (size_t)N * 64;              // N+1 (sentinel -1e30)
    float* a_dst    = a_src + (N + 1);                 // N
    int*   cnt      = (int*)(a_dst + N);               // N
    int*   rowstart = cnt + N;                         // N
    int*   hist     = rowstart + N;                    // M
    int*   rstart   = hist + M;                        // M
    int*   bsum     = rstart + M;                      // 256
    int*   boff     = bsum + 256;                      // 256
    int*   csr      = boff + 256;                      // CSRSZ
    unsigned short* wf = (unsigned short*)(csr + CSRSZ);
    unsigned short* W1hi = wf;
    unsigned short* W1lo = wf + 8192;
    unsigned short* W2hi = wf + 16384;
    unsigned short* W2lo = wf + 24576;
    float* wsm      = (float*)(wf + 32768);            // 4
    unsigned* ebuf  = (unsigned*)D;

    gat_input_kernel<<<(N + 3) / 4, 256, 0, stream>>>(x, Wg, att_s, att_d, A, a_src, a_dst, N,
                                                      W1l, W1r, W2l, W2r,
                                                      W1hi, W1lo, W2hi, W2lo, alpha, wsm);

    edge_hist_kernel<<<NCHUNK, 1024, 0, stream>>>(dst, hist, E, NBK);
    int NB = (M + 1023) / 1024;
    scan_reduce_kernel<<<NB, 256, 0, stream>>>(hist, bsum, M);
    scan_spine_kernel<<<1, 256, 0, stream>>>(bsum, boff, NB);
    scan_apply_kernel<<<NB, 256, 0, stream>>>(hist, boff, rstart, M);
    edge_scatter_kernel<<<NCHUNK, 1024, 0, stream>>>(src, dst, rstart, ebuf, E, NBK);
    bucket_build_kernel<<<NBK, 256, 0, stream>>>(ebuf, rstart, cnt, rowstart, csr, E, N, NBK);

    gat_gather_kernel<<<(N + 15) / 16, 256, 0, stream>>>(A, a_src, a_dst, bg,
                                                         rowstart, cnt, csr, wsm, B, D, N);

    sage_gemm_kernel<<<(N + 63) / 64, 256, 0, stream>>>(B, W1hi, W1lo, b1, A, B, N);
    sage_post_kernel<<<(N + 15) / 16, 256, 0, stream>>>(A, B, rowstart, cnt, csr, wsm, 2, B, D, N);

    sage_gemm_kernel<<<(N + 63) / 64, 256, 0, stream>>>(B, W2hi, W2lo, b2, A, B, N);
    sage_post_kernel<<<(N + 15) / 16, 256, 0, stream>>>(A, B, rowstart, cnt, csr, wsm, 3, nullptr, D, N);

    link_pred_kernel<<<(EL + 15) / 16, 256, 0, stream>>>(eli, D, (float*)d_out, EL);
}

// Round 13
// 346.737 us; speedup vs baseline: 1.0592x; 1.0115x over previous
//
#include <hip/hip_runtime.h>
#include <math.h>
#include <float.h>

#define NEG_SLOPE 0.2f
#define NCHUNK 128   // edge-array chunks for the deterministic scatter

typedef short short8 __attribute__((ext_vector_type(8)));
typedef float f32x4  __attribute__((ext_vector_type(4)));

__device__ __forceinline__ unsigned short bf16hi(float x) {
    unsigned u = __float_as_uint(x);
    return (unsigned short)((u + 0x7FFFu + ((u >> 16) & 1u)) >> 16);
}
__device__ __forceinline__ float bf16tof(unsigned short h) {
    return __uint_as_float(((unsigned)h) << 16);
}

// K1: h = x @ W_gat (N x 11 @ 11 x 64) fp32, a_src/a_dst; blocks 0-7 also do
// weight prep; block 8 zeroes sentinel row N and sets a_src[N] = -1e30.
__global__ __launch_bounds__(256) void gat_input_kernel(
    const float* __restrict__ x, const float* __restrict__ Wg,
    const float* __restrict__ att_src, const float* __restrict__ att_dst,
    float* __restrict__ h, float* __restrict__ a_src, float* __restrict__ a_dst, int N,
    const float* __restrict__ W1l, const float* __restrict__ W1r,
    const float* __restrict__ W2l, const float* __restrict__ W2r,
    unsigned short* __restrict__ W1hi, unsigned short* __restrict__ W1lo,
    unsigned short* __restrict__ W2hi, unsigned short* __restrict__ W2lo,
    const float* __restrict__ alpha, float* __restrict__ wsm)
{
    if (blockIdx.x < 8) {
        if (blockIdx.x == 0 && threadIdx.x == 0) {
            float m = alpha[0];
            for (int i = 1; i < 4; i++) m = fmaxf(m, alpha[i]);
            float e[4], s = 0.f;
            for (int i = 0; i < 4; i++) { e[i] = expf(alpha[i] - m); s += e[i]; }
            for (int i = 0; i < 4; i++) wsm[i] = e[i] / s;
        }
        int which = blockIdx.x >> 2;
        const float* Wl = which ? W2l : W1l;
        const float* Wr = which ? W2r : W1r;
        unsigned short* Whi = which ? W2hi : W1hi;
        unsigned short* Wlo = which ? W2lo : W1lo;
        int idx = (blockIdx.x & 3) * 256 + threadIdx.x;
        int kc = idx >> 9, rem = idx & 511;
        int t = rem >> 6, ln = rem & 63;
        int quad = ln >> 4, col16 = ln & 15;
        int c = t * 16 + col16;
        #pragma unroll
        for (int j = 0; j < 8; j++) {
            int k = kc * 32 + quad * 8 + j;
            float w = (c < 64) ? Wl[k * 64 + c] : Wr[k * 64 + (c - 64)];
            unsigned short hi = bf16hi(w);
            unsigned short lo = bf16hi(w - bf16tof(hi));
            Whi[(size_t)idx * 8 + j] = hi;
            Wlo[(size_t)idx * 8 + j] = lo;
        }
    } else if (blockIdx.x == 8) {
        if (threadIdx.x < 64) h[(size_t)N * 64 + threadIdx.x] = 0.f;
        if (threadIdx.x == 64) a_src[N] = -1e30f;
    }
    __shared__ float Wl[11 * 64];
    int tid = threadIdx.x;
    for (int i = tid; i < 11 * 64; i += 256) Wl[i] = Wg[i];
    __syncthreads();
    int lane = tid & 63;
    int n = blockIdx.x * 4 + (tid >> 6);
    if (n >= N) return;
    float xv = (lane < 11) ? x[n * 11 + lane] : 0.f;
    float acc = 0.f;
    #pragma unroll
    for (int k = 0; k < 11; k++) acc += __shfl(xv, k, 64) * Wl[k * 64 + lane];
    h[(size_t)n * 64 + lane] = acc;
    float ps = acc * att_src[lane];
    float pd = acc * att_dst[lane];
    for (int off = 32; off; off >>= 1) {
        ps += __shfl_down(ps, off, 64);
        pd += __shfl_down(pd, off, 64);
    }
    if (lane == 0) { a_src[n] = ps; a_dst[n] = pd; }
}

// ---- Chunked CSR construction (bucket = dst >> 7; no global atomics) ----

__global__ __launch_bounds__(1024) void edge_hist_kernel(
    const int* __restrict__ dst, int* __restrict__ hist, int E, int NBK)
{
    __shared__ int c[1024];
    int t = threadIdx.x;
    c[t] = 0;
    __syncthreads();
    int chunk = (E + NCHUNK - 1) / NCHUNK;
    int lo = blockIdx.x * chunk;
    int hi = lo + chunk; if (hi > E) hi = E;
    for (int i = lo + t; i < hi; i += 1024)
        atomicAdd(&c[dst[i] >> 7], 1);
    __syncthreads();
    if (t < NBK) hist[t * NCHUNK + blockIdx.x] = c[t];
}

__global__ __launch_bounds__(1024) void edge_scatter_kernel(
    const int* __restrict__ src, const int* __restrict__ dst,
    const int* __restrict__ rstart, unsigned* __restrict__ ebuf, int E, int NBK)
{
    __shared__ int cur[1024];
    int t = threadIdx.x;
    if (t < NBK) cur[t] = rstart[t * NCHUNK + blockIdx.x];
    __syncthreads();
    int chunk = (E + NCHUNK - 1) / NCHUNK;
    int lo = blockIdx.x * chunk;
    int hi = lo + chunk; if (hi > E) hi = E;
    for (int i = lo + t; i < hi; i += 1024) {
        int d = dst[i];
        int p = atomicAdd(&cur[d >> 7], 1);
        ebuf[p] = ((unsigned)src[i] << 7) | (unsigned)(d & 127);
    }
}

// ---- exclusive scan: reduce + (spine folded into apply) ----
__global__ __launch_bounds__(256) void scan_reduce_kernel(
    const int* __restrict__ v, int* __restrict__ bsum, int M)
{
    __shared__ int s[256];
    int t = threadIdx.x;
    int base = blockIdx.x * 1024 + t * 4;
    int sum = 0;
    #pragma unroll
    for (int j = 0; j < 4; j++) { int idx = base + j; if (idx < M) sum += v[idx]; }
    s[t] = sum; __syncthreads();
    for (int off = 128; off; off >>= 1) {
        if (t < off) s[t] += s[t + off];
        __syncthreads();
    }
    if (t == 0) bsum[blockIdx.x] = s[0];
}

__global__ __launch_bounds__(256) void scan_apply_kernel(
    const int* __restrict__ v, const int* __restrict__ bsum,
    int* __restrict__ out, int M, int NB)
{
    __shared__ int s[256];
    int t = threadIdx.x;
    // local spine: inclusive scan of bsum, take prefix for this block
    int bv = (t < NB) ? bsum[t] : 0;
    s[t] = bv; __syncthreads();
    for (int off = 1; off < 256; off <<= 1) {
        int xx = (t >= off) ? s[t - off] : 0;
        __syncthreads();
        s[t] += xx;
        __syncthreads();
    }
    int blockoff = (blockIdx.x == 0) ? 0 : s[blockIdx.x - 1];
    __syncthreads();
    int base = blockIdx.x * 1024;
    int vv[4]; int sum = 0;
    #pragma unroll
    for (int j = 0; j < 4; j++) {
        int idx = base + t * 4 + j;
        vv[j] = (idx < M) ? v[idx] : 0;
        sum += vv[j];
    }
    s[t] = sum; __syncthreads();
    for (int off = 1; off < 256; off <<= 1) {
        int xx = (t >= off) ? s[t - off] : 0;
        __syncthreads();
        s[t] += xx;
        __syncthreads();
    }
    int ex = s[t] - sum + blockoff;
    #pragma unroll
    for (int j = 0; j < 4; j++) {
        int idx = base + t * 4 + j;
        if (idx < M) out[idx] = ex;
        ex += vv[j];
    }
}

// one workgroup per bucket: LDS counts -> padded LDS scan -> cnt/rowstart -> csr (+pads)
__global__ __launch_bounds__(256) void bucket_build_kernel(
    const unsigned* __restrict__ ebuf, const int* __restrict__ rstart,
    int* __restrict__ cnt, int* __restrict__ rowstart,
    int* __restrict__ csr, int E, int N, int NBK)
{
    __shared__ int c[128];
    __shared__ int rs[128];
    __shared__ int cur[128];
    int b = blockIdx.x, t = threadIdx.x;
    if (t < 128) { c[t] = 0; cur[t] = 0; }
    __syncthreads();
    int beg = rstart[b * NCHUNK];
    int end = (b == NBK - 1) ? E : rstart[(b + 1) * NCHUNK];
    int n = end - beg;
    int pbeg = beg + 384 * b;
    for (int j = t; j < n; j += 256)
        atomicAdd(&c[ebuf[beg + j] & 127u], 1);
    __syncthreads();
    int myc = (t < 128) ? c[t] : 0;
    int mypc = (myc + 3) & ~3;
    if (t < 128) rs[t] = mypc;
    __syncthreads();
    for (int off = 1; off < 128; off <<= 1) {
        int v = (t < 128 && t >= off) ? rs[t - off] : 0;
        __syncthreads();
        if (t < 128) rs[t] += v;
        __syncthreads();
    }
    int ex = (t < 128) ? (rs[t] - mypc) : 0;
    __syncthreads();
    if (t < 128) rs[t] = ex;
    int base = b << 7;
    if (t < 128 && base + t < N) {
        cnt[base + t] = myc;
        rowstart[base + t] = pbeg + ex;
    }
    __syncthreads();
    for (int j = t; j < n; j += 256) {
        unsigned e = ebuf[beg + j];
        int d = (int)(e & 127u);
        int p = atomicAdd(&cur[d], 1);
        csr[pbeg + rs[d] + p] = (int)(e >> 7);
    }
    __syncthreads();
    if (t < 128) {
        for (int k = myc; k < mypc; k++) csr[pbeg + rs[t] + k] = N;
    }
}

// K2: GAT gather — 4 dst nodes per wave, 16 lanes per node, 8-deep load batches.
__global__ __launch_bounds__(256) void gat_gather_kernel(
    const float* __restrict__ h, const float* __restrict__ a_src,
    const float* __restrict__ a_dst, const float* __restrict__ bg,
    const int* __restrict__ rowstart, const int* __restrict__ cnt,
    const int* __restrict__ csr, const float* __restrict__ wsm,
    float* __restrict__ hgat, float* __restrict__ outD, int N)
{
    const float4* __restrict__ h4 = (const float4*)h;
    int tid = threadIdx.x;
    int lane = tid & 63;
    int g = lane >> 4, sub = lane & 15;
    int gl = g << 4;
    int d = blockIdx.x * 16 + (tid >> 6) * 4 + g;
    if (d >= N) return;
    float ad = a_dst[d];
    int beg = rowstart[d], deg = cnt[d];
    int degp = (deg + 3) & ~3;
    float a0 = a_src[d] + ad;
    float lg0 = a0 > 0.f ? a0 : NEG_SLOPE * a0;
    float w_self = expf(lg0);
    float4 accA = h4[(size_t)d * 16 + sub];
    accA.x *= w_self; accA.y *= w_self; accA.z *= w_self; accA.w *= w_self;
    float4 accB = make_float4(0.f, 0.f, 0.f, 0.f);
    float l_lane = 0.f;
    for (int base = 0; base < degp; base += 16) {
        int nvc = degp - base; if (nvc > 16) nvc = 16;
        int sid = (sub < nvc) ? csr[beg + base + sub] : N;
        float aa = a_src[sid] + ad;
        float lg = aa > 0.f ? aa : NEG_SLOPE * aa;
        float w = expf(lg);
        l_lane += w;
        int j = 0;
        for (; j + 8 <= nvc; j += 8) {
            int   i0 = __shfl(sid, gl + j,     64); float w0 = __shfl(w, gl + j,     64);
            int   i1 = __shfl(sid, gl + j + 1, 64); float w1 = __shfl(w, gl + j + 1, 64);
            int   i2 = __shfl(sid, gl + j + 2, 64); float w2 = __shfl(w, gl + j + 2, 64);
            int   i3 = __shfl(sid, gl + j + 3, 64); float w3 = __shfl(w, gl + j + 3, 64);
            int   i4 = __shfl(sid, gl + j + 4, 64); float w4 = __shfl(w, gl + j + 4, 64);
            int   i5 = __shfl(sid, gl + j + 5, 64); float w5 = __shfl(w, gl + j + 5, 64);
            int   i6 = __shfl(sid, gl + j + 6, 64); float w6 = __shfl(w, gl + j + 6, 64);
            int   i7 = __shfl(sid, gl + j + 7, 64); float w7 = __shfl(w, gl + j + 7, 64);
            float4 v0 = h4[(size_t)i0 * 16 + sub];
            float4 v1 = h4[(size_t)i1 * 16 + sub];
            float4 v2 = h4[(size_t)i2 * 16 + sub];
            float4 v3 = h4[(size_t)i3 * 16 + sub];
            float4 v4 = h4[(size_t)i4 * 16 + sub];
            float4 v5 = h4[(size_t)i5 * 16 + sub];
            float4 v6 = h4[(size_t)i6 * 16 + sub];
            float4 v7 = h4[(size_t)i7 * 16 + sub];
            accA.x += w0 * v0.x + w1 * v1.x + w2 * v2.x + w3 * v3.x;
            accA.y += w0 * v0.y + w1 * v1.y + w2 * v2.y + w3 * v3.y;
            accA.z += w0 * v0.z + w1 * v1.z + w2 * v2.z + w3 * v3.z;
            accA.w += w0 * v0.w + w1 * v1.w + w2 * v2.w + w3 * v3.w;
            accB.x += w4 * v4.x + w5 * v5.x + w6 * v6.x + w7 * v7.x;
            accB.y += w4 * v4.y + w5 * v5.y + w6 * v6.y + w7 * v7.y;
            accB.z += w4 * v4.z + w5 * v5.z + w6 * v6.z + w7 * v7.z;
            accB.w += w4 * v4.w + w5 * v5.w + w6 * v6.w + w7 * v7.w;
        }
        for (; j < nvc; j += 4) {
            int   i0 = __shfl(sid, gl + j,     64); float w0 = __shfl(w, gl + j,     64);
            int   i1 = __shfl(sid, gl + j + 1, 64); float w1 = __shfl(w, gl + j + 1, 64);
            int   i2 = __shfl(sid, gl + j + 2, 64); float w2 = __shfl(w, gl + j + 2, 64);
            int   i3 = __shfl(sid, gl + j + 3, 64); float w3 = __shfl(w, gl + j + 3, 64);
            float4 v0 = h4[(size_t)i0 * 16 + sub];
            float4 v1 = h4[(size_t)i1 * 16 + sub];
            float4 v2 = h4[(size_t)i2 * 16 + sub];
            float4 v3 = h4[(size_t)i3 * 16 + sub];
            accA.x += w0 * v0.x + w1 * v1.x + w2 * v2.x + w3 * v3.x;
            accA.y += w0 * v0.y + w1 * v1.y + w2 * v2.y + w3 * v3.y;
            accA.z += w0 * v0.z + w1 * v1.z + w2 * v2.z + w3 * v3.z;
            accA.w += w0 * v0.w + w1 * v1.w + w2 * v2.w + w3 * v3.w;
        }
    }
    #pragma unroll
    for (int off = 1; off < 16; off <<= 1) l_lane += __shfl_xor(l_lane, off, 64);
    float l = l_lane + w_self;
    float inv = 1.0f / (l + 1e-16f);
    float4 bb = ((const float4*)bg)[sub];
    float4 out;
    out.x = (accA.x + accB.x) * inv + bb.x;
    out.y = (accA.y + accB.y) * inv + bb.y;
    out.z = (accA.z + accB.z) * inv + bb.z;
    out.w = (accA.w + accB.w) * inv + bb.w;
    size_t idx = (size_t)d * 16 + sub;
    ((float4*)hgat)[idx] = out;
    float w0 = wsm[0];
    float4 o; o.x = w0 * out.x; o.y = w0 * out.y; o.z = w0 * out.z; o.w = w0 * out.w;
    ((float4*)outD)[idx] = o;
}

// K6: dense GEMM [P|Q] = hin @ [Wl|Wr] (+b on Q half) via mfma 16x16x32 bf16x3.
__global__ __launch_bounds__(256) void sage_gemm_kernel(
    const float* __restrict__ hin,
    const unsigned short* __restrict__ Whi, const unsigned short* __restrict__ Wlo,
    const float* __restrict__ bvec,
    float* __restrict__ P, float* __restrict__ Q, int N)
{
    int wave = threadIdx.x >> 6, lane = threadIdx.x & 63;
    int base = blockIdx.x * 64 + wave * 16;
    if (base >= N) return;
    int quad = lane >> 4, col16 = lane & 15;
    int m = base + col16;
    int mc = m < N ? m : N - 1;
    f32x4 acc[8];
    #pragma unroll
    for (int t = 0; t < 8; t++) acc[t] = (f32x4){0.f, 0.f, 0.f, 0.f};
    #pragma unroll
    for (int kc = 0; kc < 2; kc++) {
        const float* ap = hin + (size_t)mc * 64 + kc * 32 + quad * 8;
        float4 va = *(const float4*)ap;
        float4 vb = *(const float4*)(ap + 4);
        float av[8] = {va.x, va.y, va.z, va.w, vb.x, vb.y, vb.z, vb.w};
        short8 ahi, alo;
        #pragma unroll
        for (int j = 0; j < 8; j++) {
            unsigned short hh = bf16hi(av[j]);
            ahi[j] = (short)hh;
            alo[j] = (short)bf16hi(av[j] - bf16tof(hh));
        }
        #pragma unroll
        for (int t = 0; t < 8; t++) {
            size_t off = ((size_t)(kc * 8 + t) * 64 + lane) * 8;
            short8 bhi = *(const short8*)(Whi + off);
            short8 blo = *(const short8*)(Wlo + off);
            acc[t] = __builtin_amdgcn_mfma_f32_16x16x32_bf16(ahi, bhi, acc[t], 0, 0, 0);
            acc[t] = __builtin_amdgcn_mfma_f32_16x16x32_bf16(alo, bhi, acc[t], 0, 0, 0);
            acc[t] = __builtin_amdgcn_mfma_f32_16x16x32_bf16(ahi, blo, acc[t], 0, 0, 0);
        }
    }
    #pragma unroll
    for (int t = 0; t < 8; t++) {
        #pragma unroll
        for (int r = 0; r < 4; r++) {
            int node = base + quad * 4 + r;
            if (node < N) {
                float v = acc[t][r];
                if (t < 4) {
                    P[(size_t)node * 64 + t * 16 + col16] = v;
                } else {
                    int c = (t - 4) * 16 + col16;
                    Q[(size_t)node * 64 + c] = v + bvec[c];
                }
            }
        }
    }
}

// K7: SAGE post — 4 dst nodes per wave, 16 lanes per node, 8-deep load batches.
__global__ __launch_bounds__(256) void sage_post_kernel(
    const float* __restrict__ P, const float* __restrict__ Q,
    const int* __restrict__ rowstart, const int* __restrict__ cnt,
    const int* __restrict__ csr, const float* __restrict__ wsm, int widx,
    float* __restrict__ hout, float* __restrict__ outD, int N)
{
    const float4* __restrict__ P4 = (const float4*)P;
    int tid = threadIdx.x;
    int lane = tid & 63;
    int g = lane >> 4, sub = lane & 15;
    int gl = g << 4;
    int d = blockIdx.x * 16 + (tid >> 6) * 4 + g;
    if (d >= N) return;
    int beg = rowstart[d], deg = cnt[d];
    int degp = (deg + 3) & ~3;
    float4 s0 = make_float4(0.f,0.f,0.f,0.f), s1 = s0, s2 = s0, s3 = s0;
    for (int base = 0; base < degp; base += 16) {
        int nvc = degp - base; if (nvc > 16) nvc = 16;
        int sid = (sub < nvc) ? csr[beg + base + sub] : N;
        int j = 0;
        for (; j + 8 <= nvc; j += 8) {
            int i0 = __shfl(sid, gl + j,     64);
            int i1 = __shfl(sid, gl + j + 1, 64);
            int i2 = __shfl(sid, gl + j + 2, 64);
            int i3 = __shfl(sid, gl + j + 3, 64);
            int i4 = __shfl(sid, gl + j + 4, 64);
            int i5 = __shfl(sid, gl + j + 5, 64);
            int i6 = __shfl(sid, gl + j + 6, 64);
            int i7 = __shfl(sid, gl + j + 7, 64);
            float4 v0 = P4[(size_t)i0 * 16 + sub];
            float4 v1 = P4[(size_t)i1 * 16 + sub];
            float4 v2 = P4[(size_t)i2 * 16 + sub];
            float4 v3 = P4[(size_t)i3 * 16 + sub];
            float4 v4 = P4[(size_t)i4 * 16 + sub];
            float4 v5 = P4[(size_t)i5 * 16 + sub];
            float4 v6 = P4[(size_t)i6 * 16 + sub];
            float4 v7 = P4[(size_t)i7 * 16 + sub];
            s0.x += v0.x + v4.x; s0.y += v0.y + v4.y; s0.z += v0.z + v4.z; s0.w += v0.w + v4.w;
            s1.x += v1.x + v5.x; s1.y += v1.y + v5.y; s1.z += v1.z + v5.z; s1.w += v1.w + v5.w;
            s2.x += v2.x + v6.x; s2.y += v2.y + v6.y; s2.z += v2.z + v6.z; s2.w += v2.w + v6.w;
            s3.x += v3.x + v7.x; s3.y += v3.y + v7.y; s3.z += v3.z + v7.z; s3.w += v3.w + v7.w;
        }
        for (; j < nvc; j += 4) {
            int i0 = __shfl(sid, gl + j,     64);
            int i1 = __shfl(sid, gl + j + 1, 64);
            int i2 = __shfl(sid, gl + j + 2, 64);
            int i3 = __shfl(sid, gl + j + 3, 64);
            float4 v0 = P4[(size_t)i0 * 16 + sub];
            float4 v1 = P4[(size_t)i1 * 16 + sub];
            float4 v2 = P4[(size_t)i2 * 16 + sub];
            float4 v3 = P4[(size_t)i3 * 16 + sub];
            s0.x += v0.x; s0.y += v0.y; s0.z += v0.z; s0.w += v0.w;
            s1.x += v1.x; s1.y += v1.y; s1.z += v1.z; s1.w += v1.w;
            s2.x += v2.x; s2.y += v2.y; s2.z += v2.z; s2.w += v2.w;
            s3.x += v3.x; s3.y += v3.y; s3.z += v3.z; s3.w += v3.w;
        }
    }
    float4 sv;
    sv.x = (s0.x + s1.x) + (s2.x + s3.x);
    sv.y = (s0.y + s1.y) + (s2.y + s3.y);
    sv.z = (s0.z + s1.z) + (s2.z + s3.z);
    sv.w = (s0.w + s1.w) + (s2.w + s3.w);
    float invd = 1.0f / fmaxf((float)deg, 1.0f);
    size_t idx = (size_t)d * 16 + sub;
    float4 q4 = ((const float4*)Q)[idx];
    float4 o;
    o.x = sv.x * invd + q4.x; o.y = sv.y * invd + q4.y;
    o.z = sv.z * invd + q4.z; o.w = sv.w * invd + q4.w;
    if (hout) ((float4*)hout)[idx] = o;
    float w = wsm[widx];
    float4 dd = ((float4*)outD)[idx];
    dd.x += w * o.x; dd.y += w * o.y; dd.z += w * o.z; dd.w += w * o.w;
    ((float4*)outD)[idx] = dd;
}

// K8: 16 lanes per label-edge (float4 rows): out[e] = dot(outf[a], outf[b])
__global__ __launch_bounds__(256) void link_pred_kernel(
    const int* __restrict__ eli, const float* __restrict__ outf,
    float* __restrict__ out, int EL)
{
    const float4* __restrict__ o4 = (const float4*)outf;
    int e = blockIdx.x * 16 + (threadIdx.x >> 4);
    int sub = threadIdx.x & 15;
    if (e >= EL) return;
    int a = eli[e], b = eli[EL + e];
    float4 pa = o4[(size_t)a * 16 + sub];
    float4 pb = o4[(size_t)b * 16 + sub];
    float p = pa.x * pb.x + pa.y * pb.y + pa.z * pb.z + pa.w * pb.w;
    for (int off = 8; off; off >>= 1) p += __shfl_xor(p, off, 64);
    if (sub == 0) out[e] = p;
}

extern "C" void kernel_launch(void* const* d_in, const int* in_sizes, int n_in,
                              void* d_out, int out_size, void* d_ws, size_t ws_size,
                              hipStream_t stream)
{
    const float* x      = (const float*)d_in[0];
    const int*   ei     = (const int*)d_in[1];
    const int*   eli    = (const int*)d_in[2];
    const float* Wg     = (const float*)d_in[3];
    const float* att_s  = (const float*)d_in[4];
    const float* att_d  = (const float*)d_in[5];
    const float* bg     = (const float*)d_in[6];
    const float* W1l    = (const float*)d_in[7];
    const float* W1r    = (const float*)d_in[8];
    const float* b1     = (const float*)d_in[9];
    const float* W2l    = (const float*)d_in[10];
    const float* W2r    = (const float*)d_in[11];
    const float* b2     = (const float*)d_in[12];
    const float* alpha  = (const float*)d_in[13];

    const int N  = in_sizes[0] / 11;
    const int E  = in_sizes[1] / 2;
    const int EL = in_sizes[2] / 2;
    const int NBK = (N + 127) >> 7;
    const int M   = NBK * NCHUNK;
    const int CSRSZ = E + 384 * NBK;

    const int* src = ei;
    const int* dst = ei + E;

    // workspace layout (A/B have a sentinel row N)
    float* A        = (float*)d_ws;                    // (N+1)*64
    float* B        = A + (size_t)(N + 1) * 64;        // (N+1)*64
    float* D        = B + (size_t)(N + 1) * 64;        // N*64 (ebuf first, then out accum)
    float* a_src    = D + (size_t)N * 64;              // N+1
    float* a_dst    = a_src + (N + 1);                 // N
    int*   cnt      = (int*)(a_dst + N);               // N
    int*   rowstart = cnt + N;                         // N
    int*   hist     = rowstart + N;                    // M
    int*   rstart   = hist + M;                        // M
    int*   bsum     = rstart + M;                      // 256
    int*   csr      = bsum + 256;                      // CSRSZ
    unsigned short* wf = (unsigned short*)(csr + CSRSZ);
    unsigned short* W1hi = wf;
    unsigned short* W1lo = wf + 8192;
    unsigned short* W2hi = wf + 16384;
    unsigned short* W2lo = wf + 24576;
    float* wsm      = (float*)(wf + 32768);            // 4
    unsigned* ebuf  = (unsigned*)D;

    gat_input_kernel<<<(N + 3) / 4, 256, 0, stream>>>(x, Wg, att_s, att_d, A, a_src, a_dst, N,
                                                      W1l, W1r, W2l, W2r,
                                                      W1hi, W1lo, W2hi, W2lo, alpha, wsm);

    edge_hist_kernel<<<NCHUNK, 1024, 0, stream>>>(dst, hist, E, NBK);
    int NB = (M + 1023) / 1024;
    scan_reduce_kernel<<<NB, 256, 0, stream>>>(hist, bsum, M);
    scan_apply_kernel<<<NB, 256, 0, stream>>>(hist, bsum, rstart, M, NB);
    edge_scatter_kernel<<<NCHUNK, 1024, 0, stream>>>(src, dst, rstart, ebuf, E, NBK);
    bucket_build_kernel<<<NBK, 256, 0, stream>>>(ebuf, rstart, cnt, rowstart, csr, E, N, NBK);

    gat_gather_kernel<<<(N + 15) / 16, 256, 0, stream>>>(A, a_src, a_dst, bg,
                                                         rowstart, cnt, csr, wsm, B, D, N);

    sage_gemm_kernel<<<(N + 63) / 64, 256, 0, stream>>>(B, W1hi, W1lo, b1, A, B, N);
    sage_post_kernel<<<(N + 15) / 16, 256, 0, stream>>>(A, B, rowstart, cnt, csr, wsm, 2, B, D, N);

    sage_gemm_kernel<<<(N + 63) / 64, 256, 0, stream>>>(B, W2hi, W2lo, b2, A, B, N);
    sage_post_kernel<<<(N + 15) / 16, 256, 0, stream>>>(A, B, rowstart, cnt, csr, wsm, 3, nullptr, D, N);

    link_pred_kernel<<<(EL + 15) / 16, 256, 0, stream>>>(eli, D, (float*)d_out, EL);
}